// Round 1
// 1520.970 us; speedup vs baseline: 1.6235x; 1.6235x over previous
//
#include <hip/hip_runtime.h>
#include <hip/hip_bf16.h>

#define N_NODES 30000
#define E_EDGES 480000
#define KSUB 32
#define NPAIR 16384

typedef __hip_bfloat16 bf16;
typedef __bf16 bf16x8 __attribute__((ext_vector_type(8)));
typedef float floatx4 __attribute__((ext_vector_type(4)));

static __device__ __forceinline__ unsigned short f2bu(float f) {
    // round-to-nearest-even f32 -> bf16 (finite inputs only)
    unsigned int u = __float_as_uint(f);
    unsigned int r = (u + 0x7fffu + ((u >> 16) & 1u)) >> 16;
    return (unsigned short)r;
}

// ---------------- weight transpose f32 -> bf16 (+K padding with zeros) ------
__global__ void transpose_pad(const float* __restrict__ W, int K, int Nd,
                              unsigned short* __restrict__ Wt, int Kpad) {
    int t = blockIdx.x * 256 + threadIdx.x;
    if (t >= Nd * Kpad) return;
    int n = t / Kpad, k = t - n * Kpad;
    Wt[t] = (k < K) ? f2bu(W[(size_t)k * Nd + n]) : (unsigned short)0;
}

// ---------------- CSR build ----------------
__global__ void edge_hist(const int* __restrict__ dst, int* __restrict__ deg) {
    int e = blockIdx.x * 256 + threadIdx.x;
    if (e < E_EDGES) atomicAdd(&deg[dst[e]], 1);
}

__global__ void scan_kernel(const int* __restrict__ deg, int N,
                            int* __restrict__ row_start, int* __restrict__ cursor) {
    __shared__ int sh[1024];
    int t = threadIdx.x;
    int chunk = (N + 1023) >> 10;
    int lo = t * chunk;
    int hi = lo + chunk; if (hi > N) hi = N;
    if (lo > N) lo = N;
    int s = 0;
    for (int i = lo; i < hi; i++) s += deg[i];
    sh[t] = s;
    __syncthreads();
    for (int off = 1; off < 1024; off <<= 1) {
        int v = (t >= off) ? sh[t - off] : 0;
        __syncthreads();
        sh[t] += v;
        __syncthreads();
    }
    int run = (t == 0) ? 0 : sh[t - 1];
    for (int i = lo; i < hi; i++) {
        row_start[i] = run; cursor[i] = run; run += deg[i];
    }
    if (t == 1023) row_start[N] = run;
}

__global__ void edge_scatter(const int* __restrict__ src, const int* __restrict__ dst,
                             int* __restrict__ cursor, int* __restrict__ csr_src) {
    int e = blockIdx.x * 256 + threadIdx.x;
    if (e < E_EDGES) {
        int p = atomicAdd(&cursor[dst[e]], 1);
        if (p >= 0 && p < E_EDGES) csr_src[p] = src[e];
    }
}

// ---------------- fused CSR aggregation (+bias)(+LN)(+relu), register-blocked
// One wave per node. Entire output row lives in registers (V-wide vector loads).
// Edge indices loaded coalesced (64 at a time) and broadcast via shfl; edges
// processed in groups of 4 so 4*R independent wide loads are in flight per wave
// (latency fix for the old serial 1-load-chain version: VALUBusy 14%, hbm 17%).
// acc = (addCenter? X[node] : 0) + sum_{j in N(node)} X[src_j]; then optional
// bias/LN/relu; store to Y[node*DOUT], zero-padding columns D..DOUT.
template <int D, int DOUT, int DO_LN, int V>
__global__ void csr_agg_ln(const float* __restrict__ X,
                           const int* __restrict__ row_start, const int* __restrict__ csr_src,
                           const float* __restrict__ bias, float* __restrict__ Y,
                           int addCenter, int doRelu) {
    static_assert(V == 1 || V == 2 || V == 4, "bad V");
    static_assert(V == 1 || (D % (64 * V) == 0 && D == DOUT), "vector path needs divisibility");
    static_assert(!DO_LN || D % (64 * V) == 0, "LN path needs full lanes");
    constexpr int R = (D + 64 * V - 1) / (64 * V);

    int node = blockIdx.x * 4 + (threadIdx.x >> 6);
    if (node >= N_NODES) return;
    int lane = threadIdx.x & 63;

    float acc[R][V];
#pragma unroll
    for (int r = 0; r < R; r++)
#pragma unroll
        for (int i = 0; i < V; i++) acc[r][i] = 0.0f;

    auto load_row = [&](const float* p, float (&v)[R][V]) {
#pragma unroll
        for (int r = 0; r < R; r++) {
            if constexpr (V == 4) {
                float4 t = *reinterpret_cast<const float4*>(p + (size_t)(r * 64 + lane) * 4);
                v[r][0] = t.x; v[r][1] = t.y; v[r][2] = t.z; v[r][3] = t.w;
            } else if constexpr (V == 2) {
                float2 t = *reinterpret_cast<const float2*>(p + (size_t)(r * 64 + lane) * 2);
                v[r][0] = t.x; v[r][1] = t.y;
            } else {
                int c = r * 64 + lane;
                v[r][0] = (c < D) ? p[c] : 0.0f;
            }
        }
    };

    if (addCenter) {
        float vc[R][V];
        load_row(X + (size_t)node * D, vc);
#pragma unroll
        for (int r = 0; r < R; r++)
#pragma unroll
            for (int i = 0; i < V; i++) acc[r][i] += vc[r][i];
    }

    int s0 = row_start[node], s1 = row_start[node + 1];
    if (s0 < 0) s0 = 0;
    if (s1 > E_EDGES) s1 = E_EDGES;
    for (int j0 = s0; j0 < s1; j0 += 64) {
        int cnt = s1 - j0; if (cnt > 64) cnt = 64;
        int myi = 0;
        if (lane < cnt) myi = csr_src[j0 + lane];
        int t = 0;
        for (; t + 4 <= cnt; t += 4) {
            int sa = __shfl(myi, t), sb = __shfl(myi, t + 1);
            int sc = __shfl(myi, t + 2), sd = __shfl(myi, t + 3);
            if ((unsigned)sa >= (unsigned)N_NODES) sa = 0;
            if ((unsigned)sb >= (unsigned)N_NODES) sb = 0;
            if ((unsigned)sc >= (unsigned)N_NODES) sc = 0;
            if ((unsigned)sd >= (unsigned)N_NODES) sd = 0;
            float va[R][V], vb[R][V], vcv[R][V], vd[R][V];
            load_row(X + (size_t)sa * D, va);
            load_row(X + (size_t)sb * D, vb);
            load_row(X + (size_t)sc * D, vcv);
            load_row(X + (size_t)sd * D, vd);
#pragma unroll
            for (int r = 0; r < R; r++)
#pragma unroll
                for (int i = 0; i < V; i++)
                    acc[r][i] += (va[r][i] + vb[r][i]) + (vcv[r][i] + vd[r][i]);
        }
        for (; t < cnt; t++) {
            int s = __shfl(myi, t);
            if ((unsigned)s >= (unsigned)N_NODES) s = 0;
            float v[R][V];
            load_row(X + (size_t)s * D, v);
#pragma unroll
            for (int r = 0; r < R; r++)
#pragma unroll
                for (int i = 0; i < V; i++) acc[r][i] += v[r][i];
        }
    }

    if (bias) {
        float vb[R][V];
        load_row(bias, vb);
#pragma unroll
        for (int r = 0; r < R; r++)
#pragma unroll
            for (int i = 0; i < V; i++) acc[r][i] += vb[r][i];
    }

    if constexpr (DO_LN) {
        float s = 0.0f;
#pragma unroll
        for (int r = 0; r < R; r++)
#pragma unroll
            for (int i = 0; i < V; i++) s += acc[r][i];
        for (int o = 32; o; o >>= 1) s += __shfl_xor(s, o);
        float mean = s * (1.0f / (float)D);
        float q = 0.0f;
#pragma unroll
        for (int r = 0; r < R; r++)
#pragma unroll
            for (int i = 0; i < V; i++) { float d = acc[r][i] - mean; q += d * d; }
        for (int o = 32; o; o >>= 1) q += __shfl_xor(q, o);
        float rs_ = rsqrtf(q * (1.0f / (float)D) + 1e-5f);
#pragma unroll
        for (int r = 0; r < R; r++)
#pragma unroll
            for (int i = 0; i < V; i++) acc[r][i] = (acc[r][i] - mean) * rs_;
    }

    if (doRelu) {
#pragma unroll
        for (int r = 0; r < R; r++)
#pragma unroll
            for (int i = 0; i < V; i++) if (acc[r][i] < 0.0f) acc[r][i] = 0.0f;
    }

    if constexpr (V == 4) {
#pragma unroll
        for (int r = 0; r < R; r++) {
            float4 t = make_float4(acc[r][0], acc[r][1], acc[r][2], acc[r][3]);
            *reinterpret_cast<float4*>(Y + (size_t)node * DOUT + (size_t)(r * 64 + lane) * 4) = t;
        }
    } else if constexpr (V == 2) {
#pragma unroll
        for (int r = 0; r < R; r++) {
            float2 t = make_float2(acc[r][0], acc[r][1]);
            *reinterpret_cast<float2*>(Y + (size_t)node * DOUT + (size_t)(r * 64 + lane) * 2) = t;
        }
    } else {
        constexpr int RO = (DOUT + 63) / 64;
#pragma unroll
        for (int r = 0; r < RO; r++) {
            int c = r * 64 + lane;
            float v = 0.0f;
            if (r < R && c < D) v = acc[r][0];
            if (c < DOUT) Y[(size_t)node * DOUT + c] = v;
        }
    }
}

// ---------------- LayerNorm(+bias)(+optional relu), f32, one wave/row (decoder mid-layer)
template <int D>
__global__ void ln_relu(const float* __restrict__ Y, const float* __restrict__ Agg,
                        const float* __restrict__ bias, float* __restrict__ Out, int doRelu) {
    int row = blockIdx.x * 4 + (threadIdx.x >> 6);
    if (row >= N_NODES) return;
    int lane = threadIdx.x & 63;
    constexpr int NV = D / 64;
    float v[NV];
    float s = 0.0f;
#pragma unroll
    for (int i = 0; i < NV; i++) {
        int c = i * 64 + lane;
        float tv = Y[(size_t)row * D + c] + bias[c];
        if (Agg) tv += Agg[(size_t)row * D + c];
        v[i] = tv; s += tv;
    }
    for (int o = 32; o; o >>= 1) s += __shfl_xor(s, o);
    float mean = s / (float)D;
    float q = 0.0f;
#pragma unroll
    for (int i = 0; i < NV; i++) { float d = v[i] - mean; q += d * d; }
    for (int o = 32; o; o >>= 1) q += __shfl_xor(q, o);
    float rs = rsqrtf(q / (float)D + 1e-5f);
#pragma unroll
    for (int i = 0; i < NV; i++) {
        int c = i * 64 + lane;
        float o = (v[i] - mean) * rs;
        if (doRelu && o < 0.0f) o = 0.0f;
        Out[(size_t)row * D + c] = o;
    }
}

// ---------------- MFMA GEMM: C[M,Nd](f32) = A[M,K](f32, cast->bf16) * Bt[Nd,K](bf16)^T (+bias)
// 128x128 tile, BK=64, 256 threads (2x2 waves of 64x64), 16x16x32 bf16 MFMA.
// A staged via float4 pair -> RNE bf16 pack -> LDS; padded LDS stride 72 shorts.
__global__ __launch_bounds__(256, 2) void gemm_bt(
    const float* __restrict__ A, int lda, const unsigned short* __restrict__ Bt,
    int M, int K, float* __restrict__ C, int ldc, const float* __restrict__ bias) {
    __shared__ __align__(16) unsigned short As[128 * 72];
    __shared__ __align__(16) unsigned short Bs[128 * 72];
    const int t = threadIdx.x;
    const int lane = t & 63;
    const int wave = t >> 6;
    const int wm = wave >> 1, wn = wave & 1;
    const int quad = lane >> 4, m16 = lane & 15;
    const int bm = blockIdx.x, bn = blockIdx.y;

    floatx4 acc[4][4];
#pragma unroll
    for (int i = 0; i < 4; i++)
#pragma unroll
        for (int j = 0; j < 4; j++)
#pragma unroll
            for (int r = 0; r < 4; r++) acc[i][j][r] = 0.0f;

    union Pk { unsigned short h[8]; uint4 v; };

    for (int k0 = 0; k0 < K; k0 += 64) {
        // stage A tile: 128 rows x 64 k = 1024 granules of 8 elems; 4 per thread
#pragma unroll
        for (int i = 0; i < 4; i++) {
            int q = i * 256 + t;
            int r = q >> 3, g = q & 7;
            int grow = bm * 128 + r;
            uint4 val = make_uint4(0u, 0u, 0u, 0u);
            if (grow < M) {
                const float* ap = A + (size_t)grow * lda + k0 + g * 8;
                float4 f0 = *reinterpret_cast<const float4*>(ap);
                float4 f1 = *reinterpret_cast<const float4*>(ap + 4);
                Pk pk;
                pk.h[0] = f2bu(f0.x); pk.h[1] = f2bu(f0.y);
                pk.h[2] = f2bu(f0.z); pk.h[3] = f2bu(f0.w);
                pk.h[4] = f2bu(f1.x); pk.h[5] = f2bu(f1.y);
                pk.h[6] = f2bu(f1.z); pk.h[7] = f2bu(f1.w);
                val = pk.v;
            }
            *reinterpret_cast<uint4*>(&As[r * 72 + g * 8]) = val;
        }
        // stage B tile (bf16 weights; rows always in range: Nd % 128 == 0)
#pragma unroll
        for (int i = 0; i < 4; i++) {
            int q = i * 256 + t;
            int r = q >> 3, g = q & 7;
            int grow = bn * 128 + r;
            uint4 val = *reinterpret_cast<const uint4*>(Bt + (size_t)grow * K + k0 + g * 8);
            *reinterpret_cast<uint4*>(&Bs[r * 72 + g * 8]) = val;
        }
        __syncthreads();
#pragma unroll
        for (int kk = 0; kk < 2; kk++) {
            bf16x8 af[4], bfr[4];
#pragma unroll
            for (int i = 0; i < 4; i++) {
                int r = wm * 64 + i * 16 + m16;
                af[i] = *reinterpret_cast<const bf16x8*>(&As[r * 72 + (kk * 4 + quad) * 8]);
            }
#pragma unroll
            for (int j = 0; j < 4; j++) {
                int r = wn * 64 + j * 16 + m16;
                bfr[j] = *reinterpret_cast<const bf16x8*>(&Bs[r * 72 + (kk * 4 + quad) * 8]);
            }
#pragma unroll
            for (int i = 0; i < 4; i++)
#pragma unroll
                for (int j = 0; j < 4; j++)
                    acc[i][j] = __builtin_amdgcn_mfma_f32_16x16x32_bf16(af[i], bfr[j], acc[i][j], 0, 0, 0);
        }
        __syncthreads();
    }
    // epilogue: C/D layout col=lane&15, row=quad*4+reg (m89-verified)
#pragma unroll
    for (int i = 0; i < 4; i++) {
        int r0 = bm * 128 + wm * 64 + i * 16 + quad * 4;
#pragma unroll
        for (int j = 0; j < 4; j++) {
            int c = bn * 128 + wn * 64 + j * 16 + m16;
            float bia = bias ? bias[c] : 0.0f;
#pragma unroll
            for (int r = 0; r < 4; r++) {
                int row = r0 + r;
                if (row < M) C[(size_t)row * ldc + c] = acc[i][j][r] + bia;
            }
        }
    }
}

// ---------------- subgraph mean pool (f32), one wave/node, float2 regs,
// coalesced index load + shfl broadcast, fully unrolled (32 independent loads)
__global__ void pool_kernel(const float* __restrict__ zn, const int* __restrict__ idx,
                            float* __restrict__ out) {
    int i = blockIdx.x * 4 + (threadIdx.x >> 6);
    if (i >= N_NODES) return;
    int lane = threadIdx.x & 63;
    int myi = 0;
    if (lane < KSUB) myi = idx[i * KSUB + lane];
    float ax = 0.0f, ay = 0.0f;
#pragma unroll
    for (int t = 0; t < KSUB; t++) {
        int s = __shfl(myi, t);
        if ((unsigned)s >= (unsigned)N_NODES) s = 0;
        float2 v = *reinterpret_cast<const float2*>(zn + (size_t)s * 128 + lane * 2);
        ax += v.x; ay += v.y;
    }
    float2 o = make_float2(ax * (1.0f / KSUB), ay * (1.0f / KSUB));
    *reinterpret_cast<float2*>(out + (size_t)i * 128 + lane * 2) = o;
}

// ---------------- batch embedding MLP (f32): [N,8] -> relu 12 -> 16
__global__ void batch_emb_kernel(const float* __restrict__ bl, const float* __restrict__ W0,
                                 const float* __restrict__ b0, const float* __restrict__ W1,
                                 const float* __restrict__ b1, float* __restrict__ out) {
    int i = blockIdx.x * 256 + threadIdx.x;
    if (i >= N_NODES) return;
    float in[8];
#pragma unroll
    for (int d = 0; d < 8; d++) in[d] = bl[(size_t)i * 8 + d];
    float h[12];
#pragma unroll
    for (int j = 0; j < 12; j++) {
        float a = b0[j];
#pragma unroll
        for (int d = 0; d < 8; d++) a += in[d] * W0[d * 12 + j];
        h[j] = a > 0.0f ? a : 0.0f;
    }
#pragma unroll
    for (int j = 0; j < 16; j++) {
        float a = b1[j];
#pragma unroll
        for (int k = 0; k < 12; k++) a += h[k] * W1[k * 16 + j];
        out[(size_t)i * 16 + j] = a;
    }
}

// ---------------- concat z_node[128] ++ batch_emb[16] -> [144] (f32)
__global__ void concat_kernel(const float* __restrict__ zn, const float* __restrict__ be,
                              float* __restrict__ znb) {
    int i = blockIdx.x;
    int t = threadIdx.x;  // 192
    if (t < 128) znb[(size_t)i * 144 + t] = zn[(size_t)i * 128 + t];
    else if (t < 144) znb[(size_t)i * 144 + t] = be[(size_t)i * 16 + (t - 128)];
}

// ---------------- bilinear discriminator, phase 2: gathered row dots
// U = z_sub @ bil_W precomputed by gemm_bt; logits_pos[p]=dot(U[pos],z_shf[pos]),
// logits_neg[p]=dot(U[pos],z_shf[neg]). One wave per pair.
__global__ void bilinear_dot(const float* __restrict__ U, const float* __restrict__ z_shf,
                             const int* __restrict__ pos, const int* __restrict__ neg,
                             float* __restrict__ out_pos, float* __restrict__ out_neg) {
    int p = blockIdx.x * 4 + (threadIdx.x >> 6);
    if (p >= NPAIR) return;
    int lane = threadIdx.x & 63;
    int ip = pos[p], in_ = neg[p];
    if ((unsigned)ip >= (unsigned)N_NODES) ip = 0;
    if ((unsigned)in_ >= (unsigned)N_NODES) in_ = 0;
    float2 u = *reinterpret_cast<const float2*>(U + (size_t)ip * 128 + lane * 2);
    float2 zp = *reinterpret_cast<const float2*>(z_shf + (size_t)ip * 128 + lane * 2);
    float2 zn = *reinterpret_cast<const float2*>(z_shf + (size_t)in_ * 128 + lane * 2);
    float vp = u.x * zp.x + u.y * zp.y;
    float vn = u.x * zn.x + u.y * zn.y;
    for (int o = 32; o; o >>= 1) { vp += __shfl_xor(vp, o); vn += __shfl_xor(vn, o); }
    if (lane == 0) { out_pos[p] = vp; out_neg[p] = vn; }
}

// ---------------- batch discriminator MLP (f32): [N,128] -> relu 64 -> 8
__global__ void bd_kernel(const float* __restrict__ z_sub, const float* __restrict__ W0,
                          const float* __restrict__ b0, const float* __restrict__ W1,
                          const float* __restrict__ b1, float* __restrict__ out) {
    __shared__ float zsh[4][128];
    __shared__ float hsh[4][64];
    int w = threadIdx.x >> 6, lane = threadIdx.x & 63;
    int node = blockIdx.x * 4 + w;
    zsh[w][lane] = z_sub[(size_t)node * 128 + lane];
    zsh[w][64 + lane] = z_sub[(size_t)node * 128 + 64 + lane];
    __syncthreads();
    float h = b0[lane];
    for (int d = 0; d < 128; d++) h += zsh[w][d] * W0[d * 64 + lane];
    if (h < 0.0f) h = 0.0f;
    hsh[w][lane] = h;
    __syncthreads();
    if (lane < 8) {
        float o = b1[lane];
        for (int l = 0; l < 64; l++) o += hsh[w][l] * W1[l * 8 + lane];
        out[(size_t)node * 8 + lane] = o;
    }
}

extern "C" void kernel_launch(void* const* d_in, const int* in_sizes, int n_in,
                              void* d_out, int out_size, void* d_ws, size_t ws_size,
                              hipStream_t stream) {
    const float* x = (const float*)d_in[0];
    const float* x_shf = (const float*)d_in[1];
    const float* blab = (const float*)d_in[2];
    const float* encW0 = (const float*)d_in[3];
    const float* encb0 = (const float*)d_in[4];
    const float* encW1 = (const float*)d_in[5];
    const float* encb1 = (const float*)d_in[6];
    const float* decW0 = (const float*)d_in[7];
    const float* decb0 = (const float*)d_in[8];
    const float* decW1 = (const float*)d_in[9];
    const float* decb1 = (const float*)d_in[10];
    const float* beW0 = (const float*)d_in[11];
    const float* beb0 = (const float*)d_in[12];
    const float* beW1 = (const float*)d_in[13];
    const float* beb1 = (const float*)d_in[14];
    const float* bdW0 = (const float*)d_in[15];
    const float* bdb0 = (const float*)d_in[16];
    const float* bdW1 = (const float*)d_in[17];
    const float* bdb1 = (const float*)d_in[18];
    const float* bilW = (const float*)d_in[19];
    const int* eidx = (const int*)d_in[20];
    const int* subidx = (const int*)d_in[21];
    const int* posi = (const int*)d_in[22];
    const int* negi = (const int*)d_in[23];
    float* out = (float*)d_out;

    char* ws = (char*)d_ws;
    size_t off = 0;
    auto alloc = [&](size_t bytes) -> void* {
        void* p = ws + off;
        off += (bytes + 255) & ~(size_t)255;
        return p;
    };
    unsigned short* encW0t = (unsigned short*)alloc((size_t)512 * 1024 * 2);
    unsigned short* encW1t = (unsigned short*)alloc((size_t)128 * 512 * 2);
    unsigned short* decW0t = (unsigned short*)alloc((size_t)512 * 192 * 2);
    unsigned short* decW1t = (unsigned short*)alloc((size_t)1024 * 512 * 2);
    unsigned short* bilWt = (unsigned short*)alloc((size_t)128 * 128 * 2);
    int* deg = (int*)alloc((size_t)N_NODES * 4);
    int* row_start = (int*)alloc((size_t)(N_NODES + 1) * 4);
    int* cursor = (int*)alloc((size_t)N_NODES * 4);
    int* csr_src = (int*)alloc((size_t)E_EDGES * 4);
    float* y0f = (float*)alloc((size_t)N_NODES * 512 * 4);    // enc/dec pre-act; dec h1 (in-place LN)
    float* agg0f = (float*)alloc((size_t)N_NODES * 512 * 4);  // enc h1 (fused agg+LN); dec agg; then U
    float* y1f = (float*)alloc((size_t)N_NODES * 128 * 4);    // aliased by znb after encoder
    float* agg1f = (float*)alloc((size_t)N_NODES * 128 * 4);  // aliased by znb/s1f after encoder
    float* znsf = (float*)alloc((size_t)N_NODES * 128 * 4);   // aliased by s1f after encoder
    float* znf = (float*)alloc((size_t)N_NODES * 128 * 4);    // persists into decoder
    float* bemb = (float*)alloc((size_t)N_NODES * 16 * 4);
    if (off > ws_size) return;  // workspace too small: fail cleanly (finite-zero signature)

    // decoder-phase aliases over the y1f/agg1f/znsf region (46.08 MB, all free after encoder)
    float* znb = y1f;                                          // 30000*144*4 = 17.28 MB
    float* s1f = (float*)((char*)y1f + (size_t)30000 * 144 * 4);  // 30000*192*4 = 23.04 MB
    float* Ubil = agg0f;                                       // U = z_sub @ bil_W (after gemm gD)

    const int* e_src = eidx;
    const int* e_dst = eidx + E_EDGES;

    // weight transposes f32 -> bf16 (pad K to multiple of 64 where needed)
    transpose_pad<<<(512 * 1024 + 255) / 256, 256, 0, stream>>>(encW0, 1024, 512, encW0t, 1024);
    transpose_pad<<<(128 * 512 + 255) / 256, 256, 0, stream>>>(encW1, 512, 128, encW1t, 512);
    transpose_pad<<<(512 * 192 + 255) / 256, 256, 0, stream>>>(decW0, 144, 512, decW0t, 192);
    transpose_pad<<<(1024 * 512 + 255) / 256, 256, 0, stream>>>(decW1, 512, 1024, decW1t, 512);
    transpose_pad<<<(128 * 128 + 255) / 256, 256, 0, stream>>>(bilW, 128, 128, bilWt, 128);

    // CSR build (keyed by dst, storing src)
    hipMemsetAsync(deg, 0, (size_t)N_NODES * 4, stream);
    edge_hist<<<E_EDGES / 256, 256, 0, stream>>>(e_dst, deg);
    scan_kernel<<<1, 1024, 0, stream>>>(deg, N_NODES, row_start, cursor);
    edge_scatter<<<E_EDGES / 256, 256, 0, stream>>>(e_src, e_dst, cursor, csr_src);

    dim3 gA(235, 4), gB(235, 1), gC(235, 4), gD(235, 8), gU(235, 1);

    // encoder, twice (x then x_shf); matmul-first so aggregation runs in the smaller dim.
    // agg+bias+LN+relu fused into one kernel per layer (addCenter=1 folds the (x+agg) term).
    for (int pass = 0; pass < 2; pass++) {
        const float* xin = pass ? x_shf : x;
        float* zn = pass ? znsf : znf;
        float* zsub_out = out + (pass ? 3840000 : 0);
        gemm_bt<<<gA, 256, 0, stream>>>(xin, 1024, encW0t, N_NODES, 1024, y0f, 512, nullptr);
        csr_agg_ln<512, 512, 1, 4><<<7500, 256, 0, stream>>>(y0f, row_start, csr_src, encb0, agg0f, 1, 1);
        gemm_bt<<<gB, 256, 0, stream>>>(agg0f, 512, encW1t, N_NODES, 512, y1f, 128, nullptr);
        csr_agg_ln<128, 128, 1, 2><<<7500, 256, 0, stream>>>(y1f, row_start, csr_src, encb1, zn, 1, 1);
        pool_kernel<<<7500, 256, 0, stream>>>(zn, subidx, zsub_out);
    }

    // batch embedding + concat (znb aliases y1f region — encoder temporaries are dead now)
    batch_emb_kernel<<<(N_NODES + 255) / 256, 256, 0, stream>>>(blab, beW0, beb0, beW1, beb1, bemb);
    concat_kernel<<<30000, 192, 0, stream>>>(znf, bemb, znb);

    // decoder (agg-first so aggregation runs in the smaller dim)
    csr_agg_ln<144, 192, 0, 1><<<7500, 256, 0, stream>>>(znb, row_start, csr_src, nullptr, s1f, 1, 0);
    gemm_bt<<<gC, 256, 0, stream>>>(s1f, 192, decW0t, N_NODES, 192, y0f, 512, nullptr);
    ln_relu<512><<<7500, 256, 0, stream>>>(y0f, nullptr, decb0, y0f, 1);  // in-place
    csr_agg_ln<512, 512, 0, 4><<<7500, 256, 0, stream>>>(y0f, row_start, csr_src, nullptr, agg0f, 1, 0);
    gemm_bt<<<gD, 256, 0, stream>>>(agg0f, 512, decW1t, N_NODES, 512, out + 7680000, 1024, decb1);

    // heads: bilinear via U = z_sub @ bil_W (agg0f region is dead after gemm gD)
    gemm_bt<<<gU, 256, 0, stream>>>(out, 128, bilWt, N_NODES, 128, Ubil, 128, nullptr);
    bilinear_dot<<<(NPAIR + 3) / 4, 256, 0, stream>>>(Ubil, out + 3840000, posi, negi,
                                                      out + 38400000, out + 38416384);
    bd_kernel<<<7500, 256, 0, stream>>>(out, bdW0, bdb0, bdW1, bdb1, out + 38432768);
}

// Round 2
// 1136.205 us; speedup vs baseline: 2.1733x; 1.3386x over previous
//
#include <hip/hip_runtime.h>
#include <hip/hip_bf16.h>

#define N_NODES 30000
#define E_EDGES 480000
#define KSUB 32
#define NPAIR 16384

typedef __hip_bfloat16 bf16;
typedef __bf16 bf16x8 __attribute__((ext_vector_type(8)));
typedef float floatx4 __attribute__((ext_vector_type(4)));

static __device__ __forceinline__ unsigned short f2bu(float f) {
    // round-to-nearest-even f32 -> bf16 (finite inputs only)
    unsigned int u = __float_as_uint(f);
    unsigned int r = (u + 0x7fffu + ((u >> 16) & 1u)) >> 16;
    return (unsigned short)r;
}
static __device__ __forceinline__ float blo(unsigned int u) { return __uint_as_float(u << 16); }
static __device__ __forceinline__ float bhi(unsigned int u) { return __uint_as_float(u & 0xffff0000u); }
static __device__ __forceinline__ unsigned int pk2(float a, float b) {
    return (unsigned int)f2bu(a) | ((unsigned int)f2bu(b) << 16);
}

// ---------------- weight transpose f32 -> bf16 (+K padding with zeros) ------
__global__ void transpose_pad(const float* __restrict__ W, int K, int Nd,
                              unsigned short* __restrict__ Wt, int Kpad) {
    int t = blockIdx.x * 256 + threadIdx.x;
    if (t >= Nd * Kpad) return;
    int n = t / Kpad, k = t - n * Kpad;
    Wt[t] = (k < K) ? f2bu(W[(size_t)k * Nd + n]) : (unsigned short)0;
}

// ---------------- CSR build ----------------
__global__ void edge_hist(const int* __restrict__ dst, int* __restrict__ deg) {
    int e = blockIdx.x * 256 + threadIdx.x;
    if (e < E_EDGES) atomicAdd(&deg[dst[e]], 1);
}

__global__ void scan_kernel(const int* __restrict__ deg, int N,
                            int* __restrict__ row_start, int* __restrict__ cursor) {
    __shared__ int sh[1024];
    int t = threadIdx.x;
    int chunk = (N + 1023) >> 10;
    int lo = t * chunk;
    int hi = lo + chunk; if (hi > N) hi = N;
    if (lo > N) lo = N;
    int s = 0;
    for (int i = lo; i < hi; i++) s += deg[i];
    sh[t] = s;
    __syncthreads();
    for (int off = 1; off < 1024; off <<= 1) {
        int v = (t >= off) ? sh[t - off] : 0;
        __syncthreads();
        sh[t] += v;
        __syncthreads();
    }
    int run = (t == 0) ? 0 : sh[t - 1];
    for (int i = lo; i < hi; i++) {
        row_start[i] = run; cursor[i] = run; run += deg[i];
    }
    if (t == 1023) row_start[N] = run;
}

__global__ void edge_scatter(const int* __restrict__ src, const int* __restrict__ dst,
                             int* __restrict__ cursor, int* __restrict__ csr_src) {
    int e = blockIdx.x * 256 + threadIdx.x;
    if (e < E_EDGES) {
        int p = atomicAdd(&cursor[dst[e]], 1);
        if (p >= 0 && p < E_EDGES) csr_src[p] = src[e];
    }
}

// ---------------- fused CSR aggregation, bf16 in / bf16 out, f32 accumulate
// One wave per node; full row in registers. Edge indices loaded coalesced and
// broadcast via shfl; edges processed in groups of 8 (independent loads in
// flight). acc = (addCenter? X[node]:0) + sum X[src_j]; +bias, LN, relu opts.
// D=512 path: one uint4 (8 bf16) per lane. Else: ushort2 units, R rounds.
// Output stride DOUT, cols D..DOUT zero-padded.
template <int D, int DOUT, int DO_LN>
__global__ void csr_agg_ln_h(const unsigned short* __restrict__ X,
                             const int* __restrict__ row_start,
                             const int* __restrict__ csr_src,
                             const float* __restrict__ bias,
                             unsigned short* __restrict__ Y,
                             int addCenter, int doRelu) {
    constexpr int VE = (D % 512 == 0) ? 8 : 2;
    constexpr int R = (D + 64 * VE - 1) / (64 * VE);
    static_assert(VE == 2 || R == 1, "VE8 path assumes single round");
    static_assert(!DO_LN || (D % (64 * VE) == 0), "LN path needs full lanes");
    constexpr int U = D / 2;      // ushort2 units (VE2 path)
    constexpr int UO = DOUT / 2;
    static_assert(D % 2 == 0 && DOUT % 2 == 0, "even dims");

    int node = blockIdx.x * 4 + (threadIdx.x >> 6);
    if (node >= N_NODES) return;
    int lane = threadIdx.x & 63;

    float acc[R][VE];
#pragma unroll
    for (int r = 0; r < R; r++)
#pragma unroll
        for (int i = 0; i < VE; i++) acc[r][i] = 0.0f;

    int s0 = row_start[node], s1 = row_start[node + 1];
    if (s0 < 0) s0 = 0;
    if (s1 > E_EDGES) s1 = E_EDGES;

    if constexpr (VE == 8) {
        auto add_u4 = [&](uint4 u) {
            acc[0][0] += blo(u.x); acc[0][1] += bhi(u.x);
            acc[0][2] += blo(u.y); acc[0][3] += bhi(u.y);
            acc[0][4] += blo(u.z); acc[0][5] += bhi(u.z);
            acc[0][6] += blo(u.w); acc[0][7] += bhi(u.w);
        };
        if (addCenter)
            add_u4(*reinterpret_cast<const uint4*>(X + (size_t)node * D + lane * 8));
        for (int j0 = s0; j0 < s1; j0 += 64) {
            int cnt = s1 - j0; if (cnt > 64) cnt = 64;
            int myi = (lane < cnt) ? csr_src[j0 + lane] : 0;
            int t = 0;
            for (; t + 8 <= cnt; t += 8) {
                uint4 raw[8];
#pragma unroll
                for (int g = 0; g < 8; g++) {
                    int s = __shfl(myi, t + g);
                    if ((unsigned)s >= (unsigned)N_NODES) s = 0;
                    raw[g] = *reinterpret_cast<const uint4*>(X + (size_t)s * D + lane * 8);
                }
#pragma unroll
                for (int g = 0; g < 8; g++) add_u4(raw[g]);
            }
            for (; t < cnt; t++) {
                int s = __shfl(myi, t);
                if ((unsigned)s >= (unsigned)N_NODES) s = 0;
                add_u4(*reinterpret_cast<const uint4*>(X + (size_t)s * D + lane * 8));
            }
        }
        if (bias) {
            const float4* bp = reinterpret_cast<const float4*>(bias + lane * 8);
            float4 b0 = bp[0], b1 = bp[1];
            acc[0][0] += b0.x; acc[0][1] += b0.y; acc[0][2] += b0.z; acc[0][3] += b0.w;
            acc[0][4] += b1.x; acc[0][5] += b1.y; acc[0][6] += b1.z; acc[0][7] += b1.w;
        }
    } else {
        auto add_u = [&](int r, unsigned int u) { acc[r][0] += blo(u); acc[r][1] += bhi(u); };
        if (addCenter) {
#pragma unroll
            for (int r = 0; r < R; r++) {
                int unit = r * 64 + lane;
                if (unit < U)
                    add_u(r, *reinterpret_cast<const unsigned int*>(X + (size_t)node * D + unit * 2));
            }
        }
        for (int j0 = s0; j0 < s1; j0 += 64) {
            int cnt = s1 - j0; if (cnt > 64) cnt = 64;
            int myi = (lane < cnt) ? csr_src[j0 + lane] : 0;
            int t = 0;
            for (; t + 8 <= cnt; t += 8) {
                unsigned int raw[8][R];
#pragma unroll
                for (int g = 0; g < 8; g++) {
                    int s = __shfl(myi, t + g);
                    if ((unsigned)s >= (unsigned)N_NODES) s = 0;
#pragma unroll
                    for (int r = 0; r < R; r++) {
                        int unit = r * 64 + lane;
                        raw[g][r] = (unit < U)
                            ? *reinterpret_cast<const unsigned int*>(X + (size_t)s * D + unit * 2)
                            : 0u;
                    }
                }
#pragma unroll
                for (int g = 0; g < 8; g++)
#pragma unroll
                    for (int r = 0; r < R; r++) add_u(r, raw[g][r]);
            }
            for (; t < cnt; t++) {
                int s = __shfl(myi, t);
                if ((unsigned)s >= (unsigned)N_NODES) s = 0;
#pragma unroll
                for (int r = 0; r < R; r++) {
                    int unit = r * 64 + lane;
                    if (unit < U)
                        add_u(r, *reinterpret_cast<const unsigned int*>(X + (size_t)s * D + unit * 2));
                }
            }
        }
        if (bias) {
#pragma unroll
            for (int r = 0; r < R; r++) {
                int unit = r * 64 + lane;
                if (unit < U) { acc[r][0] += bias[unit * 2]; acc[r][1] += bias[unit * 2 + 1]; }
            }
        }
    }

    if constexpr (DO_LN) {
        float s = 0.0f;
#pragma unroll
        for (int r = 0; r < R; r++)
#pragma unroll
            for (int i = 0; i < VE; i++) s += acc[r][i];
        for (int o = 32; o; o >>= 1) s += __shfl_xor(s, o);
        float mean = s * (1.0f / (float)D);
        float q = 0.0f;
#pragma unroll
        for (int r = 0; r < R; r++)
#pragma unroll
            for (int i = 0; i < VE; i++) { float d = acc[r][i] - mean; q += d * d; }
        for (int o = 32; o; o >>= 1) q += __shfl_xor(q, o);
        float rs_ = rsqrtf(q * (1.0f / (float)D) + 1e-5f);
#pragma unroll
        for (int r = 0; r < R; r++)
#pragma unroll
            for (int i = 0; i < VE; i++) acc[r][i] = (acc[r][i] - mean) * rs_;
    }

    if (doRelu) {
#pragma unroll
        for (int r = 0; r < R; r++)
#pragma unroll
            for (int i = 0; i < VE; i++) if (acc[r][i] < 0.0f) acc[r][i] = 0.0f;
    }

    if constexpr (VE == 8) {
        uint4 o = make_uint4(pk2(acc[0][0], acc[0][1]), pk2(acc[0][2], acc[0][3]),
                             pk2(acc[0][4], acc[0][5]), pk2(acc[0][6], acc[0][7]));
        *reinterpret_cast<uint4*>(Y + (size_t)node * DOUT + lane * 8) = o;
    } else {
        constexpr int RO = (UO + 63) / 64;
#pragma unroll
        for (int r = 0; r < RO; r++) {
            int unit = r * 64 + lane;
            if (unit < UO) {
                unsigned int v = 0u;
                if (r < R && unit < U) v = pk2(acc[r][0], acc[r][1]);
                *reinterpret_cast<unsigned int*>(Y + (size_t)node * DOUT + unit * 2) = v;
            }
        }
    }
}

// ---------------- LayerNorm(+bias)+relu over 512-wide bf16 rows, in-place safe
__global__ void ln_relu_h512(const unsigned short* __restrict__ Yin,
                             const float* __restrict__ bias,
                             unsigned short* __restrict__ Out) {
    int row = blockIdx.x * 4 + (threadIdx.x >> 6);
    if (row >= N_NODES) return;
    int lane = threadIdx.x & 63;
    uint4 u = *reinterpret_cast<const uint4*>(Yin + (size_t)row * 512 + lane * 8);
    const float4* bp = reinterpret_cast<const float4*>(bias + lane * 8);
    float4 b0 = bp[0], b1 = bp[1];
    float v[8];
    v[0] = blo(u.x) + b0.x; v[1] = bhi(u.x) + b0.y;
    v[2] = blo(u.y) + b0.z; v[3] = bhi(u.y) + b0.w;
    v[4] = blo(u.z) + b1.x; v[5] = bhi(u.z) + b1.y;
    v[6] = blo(u.w) + b1.z; v[7] = bhi(u.w) + b1.w;
    float s = 0.0f;
#pragma unroll
    for (int i = 0; i < 8; i++) s += v[i];
    for (int o = 32; o; o >>= 1) s += __shfl_xor(s, o);
    float mean = s * (1.0f / 512.0f);
    float q = 0.0f;
#pragma unroll
    for (int i = 0; i < 8; i++) { float d = v[i] - mean; q += d * d; }
    for (int o = 32; o; o >>= 1) q += __shfl_xor(q, o);
    float rs = rsqrtf(q * (1.0f / 512.0f) + 1e-5f);
#pragma unroll
    for (int i = 0; i < 8; i++) {
        float o = (v[i] - mean) * rs;
        v[i] = o > 0.0f ? o : 0.0f;
    }
    uint4 o = make_uint4(pk2(v[0], v[1]), pk2(v[2], v[3]), pk2(v[4], v[5]), pk2(v[6], v[7]));
    *reinterpret_cast<uint4*>(Out + (size_t)row * 512 + lane * 8) = o;
}

// ---------------- MFMA GEMM: C[M,Nd] = A[M,K] * Bt[Nd,K]^T (+bias)
// A: f32 (RNE-cast while staging) or bf16 (direct uint4 copy). C: f32 or bf16.
// 128x128 tile, BK=64, 256 threads (2x2 waves), 16x16x32 bf16 MFMA, LDS stride 72.
template <int ABF, int CBF>
__global__ __launch_bounds__(256, 2) void gemm_bt(
    const void* __restrict__ A_, int lda, const unsigned short* __restrict__ Bt,
    int M, int K, void* __restrict__ C_, int ldc, const float* __restrict__ bias) {
    __shared__ __align__(16) unsigned short As[128 * 72];
    __shared__ __align__(16) unsigned short Bs[128 * 72];
    const int t = threadIdx.x;
    const int lane = t & 63;
    const int wave = t >> 6;
    const int wm = wave >> 1, wn = wave & 1;
    const int quad = lane >> 4, m16 = lane & 15;
    const int bm = blockIdx.x, bn = blockIdx.y;

    floatx4 acc[4][4];
#pragma unroll
    for (int i = 0; i < 4; i++)
#pragma unroll
        for (int j = 0; j < 4; j++)
#pragma unroll
            for (int r = 0; r < 4; r++) acc[i][j][r] = 0.0f;

    union Pk { unsigned short h[8]; uint4 v; };

    for (int k0 = 0; k0 < K; k0 += 64) {
        // stage A tile: 128 rows x 64 k = 1024 granules of 8 elems; 4 per thread
#pragma unroll
        for (int i = 0; i < 4; i++) {
            int q = i * 256 + t;
            int r = q >> 3, g = q & 7;
            int grow = bm * 128 + r;
            uint4 val = make_uint4(0u, 0u, 0u, 0u);
            if (grow < M) {
                if constexpr (ABF) {
                    const unsigned short* Ah = (const unsigned short*)A_;
                    val = *reinterpret_cast<const uint4*>(Ah + (size_t)grow * lda + k0 + g * 8);
                } else {
                    const float* ap = (const float*)A_ + (size_t)grow * lda + k0 + g * 8;
                    float4 f0 = *reinterpret_cast<const float4*>(ap);
                    float4 f1 = *reinterpret_cast<const float4*>(ap + 4);
                    Pk pk;
                    pk.h[0] = f2bu(f0.x); pk.h[1] = f2bu(f0.y);
                    pk.h[2] = f2bu(f0.z); pk.h[3] = f2bu(f0.w);
                    pk.h[4] = f2bu(f1.x); pk.h[5] = f2bu(f1.y);
                    pk.h[6] = f2bu(f1.z); pk.h[7] = f2bu(f1.w);
                    val = pk.v;
                }
            }
            *reinterpret_cast<uint4*>(&As[r * 72 + g * 8]) = val;
        }
        // stage B tile (bf16 weights; rows always in range: Nd % 128 == 0)
#pragma unroll
        for (int i = 0; i < 4; i++) {
            int q = i * 256 + t;
            int r = q >> 3, g = q & 7;
            int grow = bn * 128 + r;
            uint4 val = *reinterpret_cast<const uint4*>(Bt + (size_t)grow * K + k0 + g * 8);
            *reinterpret_cast<uint4*>(&Bs[r * 72 + g * 8]) = val;
        }
        __syncthreads();
#pragma unroll
        for (int kk = 0; kk < 2; kk++) {
            bf16x8 af[4], bfr[4];
#pragma unroll
            for (int i = 0; i < 4; i++) {
                int r = wm * 64 + i * 16 + m16;
                af[i] = *reinterpret_cast<const bf16x8*>(&As[r * 72 + (kk * 4 + quad) * 8]);
            }
#pragma unroll
            for (int j = 0; j < 4; j++) {
                int r = wn * 64 + j * 16 + m16;
                bfr[j] = *reinterpret_cast<const bf16x8*>(&Bs[r * 72 + (kk * 4 + quad) * 8]);
            }
#pragma unroll
            for (int i = 0; i < 4; i++)
#pragma unroll
                for (int j = 0; j < 4; j++)
                    acc[i][j] = __builtin_amdgcn_mfma_f32_16x16x32_bf16(af[i], bfr[j], acc[i][j], 0, 0, 0);
        }
        __syncthreads();
    }
    // epilogue: C/D layout col=lane&15, row=quad*4+reg (m89-verified)
#pragma unroll
    for (int i = 0; i < 4; i++) {
        int r0 = bm * 128 + wm * 64 + i * 16 + quad * 4;
#pragma unroll
        for (int j = 0; j < 4; j++) {
            int c = bn * 128 + wn * 64 + j * 16 + m16;
            float bia = bias ? bias[c] : 0.0f;
#pragma unroll
            for (int r = 0; r < 4; r++) {
                int row = r0 + r;
                if (row < M) {
                    float val = acc[i][j][r] + bia;
                    if constexpr (CBF)
                        ((unsigned short*)C_)[(size_t)row * ldc + c] = f2bu(val);
                    else
                        ((float*)C_)[(size_t)row * ldc + c] = val;
                }
            }
        }
    }
}

// ---------------- subgraph mean pool: zn bf16 [N,128] -> out f32 [N,128]
__global__ void pool_kernel_h(const unsigned short* __restrict__ zn, const int* __restrict__ idx,
                              float* __restrict__ out) {
    int i = blockIdx.x * 4 + (threadIdx.x >> 6);
    if (i >= N_NODES) return;
    int lane = threadIdx.x & 63;
    int myi = (lane < KSUB) ? idx[i * KSUB + lane] : 0;
    float ax = 0.0f, ay = 0.0f;
#pragma unroll
    for (int t = 0; t < KSUB; t++) {
        int s = __shfl(myi, t);
        if ((unsigned)s >= (unsigned)N_NODES) s = 0;
        unsigned int u = *reinterpret_cast<const unsigned int*>(zn + (size_t)s * 128 + lane * 2);
        ax += blo(u); ay += bhi(u);
    }
    *reinterpret_cast<float2*>(out + (size_t)i * 128 + lane * 2) =
        make_float2(ax * (1.0f / KSUB), ay * (1.0f / KSUB));
}

// ---------------- batch embedding MLP (f32): [N,8] -> relu 12 -> 16
__global__ void batch_emb_kernel(const float* __restrict__ bl, const float* __restrict__ W0,
                                 const float* __restrict__ b0, const float* __restrict__ W1,
                                 const float* __restrict__ b1, float* __restrict__ out) {
    int i = blockIdx.x * 256 + threadIdx.x;
    if (i >= N_NODES) return;
    float in[8];
#pragma unroll
    for (int d = 0; d < 8; d++) in[d] = bl[(size_t)i * 8 + d];
    float h[12];
#pragma unroll
    for (int j = 0; j < 12; j++) {
        float a = b0[j];
#pragma unroll
        for (int d = 0; d < 8; d++) a += in[d] * W0[d * 12 + j];
        h[j] = a > 0.0f ? a : 0.0f;
    }
#pragma unroll
    for (int j = 0; j < 16; j++) {
        float a = b1[j];
#pragma unroll
        for (int k = 0; k < 12; k++) a += h[k] * W1[k * 16 + j];
        out[(size_t)i * 16 + j] = a;
    }
}

// ---------------- concat zn bf16[128] ++ bemb f32[16] -> znb bf16[144]
__global__ void concat_kernel_h(const unsigned short* __restrict__ zn,
                                const float* __restrict__ be,
                                unsigned short* __restrict__ znb) {
    int i = blockIdx.x;
    int t = threadIdx.x;  // 192
    if (t < 128) znb[(size_t)i * 144 + t] = zn[(size_t)i * 128 + t];
    else if (t < 144) znb[(size_t)i * 144 + t] = f2bu(be[(size_t)i * 16 + (t - 128)]);
}

// ---------------- bilinear discriminator, phase 2: gathered row dots (f32)
__global__ void bilinear_dot(const float* __restrict__ U, const float* __restrict__ z_shf,
                             const int* __restrict__ pos, const int* __restrict__ neg,
                             float* __restrict__ out_pos, float* __restrict__ out_neg) {
    int p = blockIdx.x * 4 + (threadIdx.x >> 6);
    if (p >= NPAIR) return;
    int lane = threadIdx.x & 63;
    int ip = pos[p], in_ = neg[p];
    if ((unsigned)ip >= (unsigned)N_NODES) ip = 0;
    if ((unsigned)in_ >= (unsigned)N_NODES) in_ = 0;
    float2 u = *reinterpret_cast<const float2*>(U + (size_t)ip * 128 + lane * 2);
    float2 zp = *reinterpret_cast<const float2*>(z_shf + (size_t)ip * 128 + lane * 2);
    float2 zn = *reinterpret_cast<const float2*>(z_shf + (size_t)in_ * 128 + lane * 2);
    float vp = u.x * zp.x + u.y * zp.y;
    float vn = u.x * zn.x + u.y * zn.y;
    for (int o = 32; o; o >>= 1) { vp += __shfl_xor(vp, o); vn += __shfl_xor(vn, o); }
    if (lane == 0) { out_pos[p] = vp; out_neg[p] = vn; }
}

// ---------------- batch discriminator MLP (f32): [N,128] -> relu 64 -> 8
__global__ void bd_kernel(const float* __restrict__ z_sub, const float* __restrict__ W0,
                          const float* __restrict__ b0, const float* __restrict__ W1,
                          const float* __restrict__ b1, float* __restrict__ out) {
    __shared__ float zsh[4][128];
    __shared__ float hsh[4][64];
    int w = threadIdx.x >> 6, lane = threadIdx.x & 63;
    int node = blockIdx.x * 4 + w;
    zsh[w][lane] = z_sub[(size_t)node * 128 + lane];
    zsh[w][64 + lane] = z_sub[(size_t)node * 128 + 64 + lane];
    __syncthreads();
    float h = b0[lane];
    for (int d = 0; d < 128; d++) h += zsh[w][d] * W0[d * 64 + lane];
    if (h < 0.0f) h = 0.0f;
    hsh[w][lane] = h;
    __syncthreads();
    if (lane < 8) {
        float o = b1[lane];
        for (int l = 0; l < 64; l++) o += hsh[w][l] * W1[l * 8 + lane];
        out[(size_t)node * 8 + lane] = o;
    }
}

extern "C" void kernel_launch(void* const* d_in, const int* in_sizes, int n_in,
                              void* d_out, int out_size, void* d_ws, size_t ws_size,
                              hipStream_t stream) {
    const float* x = (const float*)d_in[0];
    const float* x_shf = (const float*)d_in[1];
    const float* blab = (const float*)d_in[2];
    const float* encW0 = (const float*)d_in[3];
    const float* encb0 = (const float*)d_in[4];
    const float* encW1 = (const float*)d_in[5];
    const float* encb1 = (const float*)d_in[6];
    const float* decW0 = (const float*)d_in[7];
    const float* decb0 = (const float*)d_in[8];
    const float* decW1 = (const float*)d_in[9];
    const float* decb1 = (const float*)d_in[10];
    const float* beW0 = (const float*)d_in[11];
    const float* beb0 = (const float*)d_in[12];
    const float* beW1 = (const float*)d_in[13];
    const float* beb1 = (const float*)d_in[14];
    const float* bdW0 = (const float*)d_in[15];
    const float* bdb0 = (const float*)d_in[16];
    const float* bdW1 = (const float*)d_in[17];
    const float* bdb1 = (const float*)d_in[18];
    const float* bilW = (const float*)d_in[19];
    const int* eidx = (const int*)d_in[20];
    const int* subidx = (const int*)d_in[21];
    const int* posi = (const int*)d_in[22];
    const int* negi = (const int*)d_in[23];
    float* out = (float*)d_out;

    char* ws = (char*)d_ws;
    size_t off = 0;
    auto alloc = [&](size_t bytes) -> void* {
        void* p = ws + off;
        off += (bytes + 255) & ~(size_t)255;
        return p;
    };
    unsigned short* encW0t = (unsigned short*)alloc((size_t)512 * 1024 * 2);
    unsigned short* encW1t = (unsigned short*)alloc((size_t)128 * 512 * 2);
    unsigned short* decW0t = (unsigned short*)alloc((size_t)512 * 192 * 2);
    unsigned short* decW1t = (unsigned short*)alloc((size_t)1024 * 512 * 2);
    unsigned short* bilWt = (unsigned short*)alloc((size_t)128 * 128 * 2);
    int* deg = (int*)alloc((size_t)N_NODES * 4);
    int* row_start = (int*)alloc((size_t)(N_NODES + 1) * 4);
    int* cursor = (int*)alloc((size_t)N_NODES * 4);
    int* csr_src = (int*)alloc((size_t)E_EDGES * 4);
    unsigned short* y0h = (unsigned short*)alloc((size_t)N_NODES * 512 * 2);   // enc/dec pre-act
    unsigned short* agg0h = (unsigned short*)alloc((size_t)N_NODES * 512 * 2); // enc h1; dec agg
    unsigned short* y1h = (unsigned short*)alloc((size_t)N_NODES * 128 * 2);   // enc layer-2 pre
    unsigned short* znh = (unsigned short*)alloc((size_t)N_NODES * 128 * 2);   // z_node (pass 0)
    unsigned short* znsh = (unsigned short*)alloc((size_t)N_NODES * 128 * 2);  // z_node shf
    unsigned short* znbh = (unsigned short*)alloc((size_t)N_NODES * 144 * 2);  // concat
    unsigned short* s1h = (unsigned short*)alloc((size_t)N_NODES * 192 * 2);   // dec agg1 (K-pad)
    float* bembf = (float*)alloc((size_t)N_NODES * 16 * 4);
    float* Ubil = (float*)alloc((size_t)N_NODES * 128 * 4);
    if (off > ws_size) return;  // workspace too small: fail cleanly

    const int* e_src = eidx;
    const int* e_dst = eidx + E_EDGES;

    // weight transposes f32 -> bf16 (pad K to multiple of 64 where needed)
    transpose_pad<<<(512 * 1024 + 255) / 256, 256, 0, stream>>>(encW0, 1024, 512, encW0t, 1024);
    transpose_pad<<<(128 * 512 + 255) / 256, 256, 0, stream>>>(encW1, 512, 128, encW1t, 512);
    transpose_pad<<<(512 * 192 + 255) / 256, 256, 0, stream>>>(decW0, 144, 512, decW0t, 192);
    transpose_pad<<<(1024 * 512 + 255) / 256, 256, 0, stream>>>(decW1, 512, 1024, decW1t, 512);
    transpose_pad<<<(128 * 128 + 255) / 256, 256, 0, stream>>>(bilW, 128, 128, bilWt, 128);

    // CSR build (keyed by dst, storing src)
    hipMemsetAsync(deg, 0, (size_t)N_NODES * 4, stream);
    edge_hist<<<E_EDGES / 256, 256, 0, stream>>>(e_dst, deg);
    scan_kernel<<<1, 1024, 0, stream>>>(deg, N_NODES, row_start, cursor);
    edge_scatter<<<E_EDGES / 256, 256, 0, stream>>>(e_src, e_dst, cursor, csr_src);

    dim3 gA(235, 4), gB(235, 1), gC(235, 4), gD(235, 8), gU(235, 1);

    // encoder, twice (x then x_shf); matmul-first so aggregation runs in the smaller dim.
    // agg+bias+LN+relu fused; all intermediates bf16 (GEMM casts A to bf16 anyway).
    for (int pass = 0; pass < 2; pass++) {
        const float* xin = pass ? x_shf : x;
        unsigned short* zn = pass ? znsh : znh;
        float* zsub_out = out + (pass ? 3840000 : 0);
        gemm_bt<0, 1><<<gA, 256, 0, stream>>>(xin, 1024, encW0t, N_NODES, 1024, y0h, 512, nullptr);
        csr_agg_ln_h<512, 512, 1><<<7500, 256, 0, stream>>>(y0h, row_start, csr_src, encb0, agg0h, 1, 1);
        gemm_bt<1, 1><<<gB, 256, 0, stream>>>(agg0h, 512, encW1t, N_NODES, 512, y1h, 128, nullptr);
        csr_agg_ln_h<128, 128, 1><<<7500, 256, 0, stream>>>(y1h, row_start, csr_src, encb1, zn, 1, 1);
        pool_kernel_h<<<7500, 256, 0, stream>>>(zn, subidx, zsub_out);
    }

    // batch embedding + concat
    batch_emb_kernel<<<(N_NODES + 255) / 256, 256, 0, stream>>>(blab, beW0, beb0, beW1, beb1, bembf);
    concat_kernel_h<<<30000, 192, 0, stream>>>(znh, bembf, znbh);

    // decoder (agg-first so aggregation runs in the smaller dim)
    csr_agg_ln_h<144, 192, 0><<<7500, 256, 0, stream>>>(znbh, row_start, csr_src, nullptr, s1h, 1, 0);
    gemm_bt<1, 1><<<gC, 256, 0, stream>>>(s1h, 192, decW0t, N_NODES, 192, y0h, 512, nullptr);
    ln_relu_h512<<<7500, 256, 0, stream>>>(y0h, decb0, y0h);  // in-place
    csr_agg_ln_h<512, 512, 0><<<7500, 256, 0, stream>>>(y0h, row_start, csr_src, nullptr, agg0h, 1, 0);
    gemm_bt<1, 0><<<gD, 256, 0, stream>>>(agg0h, 512, decW1t, N_NODES, 512, out + 7680000, 1024, decb1);

    // heads: bilinear via U = z_sub @ bil_W
    gemm_bt<0, 0><<<gU, 256, 0, stream>>>(out, 128, bilWt, N_NODES, 128, Ubil, 128, nullptr);
    bilinear_dot<<<(NPAIR + 3) / 4, 256, 0, stream>>>(Ubil, out + 3840000, posi, negi,
                                                      out + 38400000, out + 38416384);
    bd_kernel<<<7500, 256, 0, stream>>>(out, bdW0, bdb0, bdW1, bdb1, out + 38432768);
}

// Round 3
// 1060.175 us; speedup vs baseline: 2.3292x; 1.0717x over previous
//
#include <hip/hip_runtime.h>
#include <hip/hip_bf16.h>

#define N_NODES 30000
#define E_EDGES 480000
#define KSUB 32
#define NPAIR 16384

typedef __hip_bfloat16 bf16;
typedef __bf16 bf16x8 __attribute__((ext_vector_type(8)));
typedef float floatx4 __attribute__((ext_vector_type(4)));

static __device__ __forceinline__ unsigned short f2bu(float f) {
    // round-to-nearest-even f32 -> bf16 (finite inputs only)
    unsigned int u = __float_as_uint(f);
    unsigned int r = (u + 0x7fffu + ((u >> 16) & 1u)) >> 16;
    return (unsigned short)r;
}
static __device__ __forceinline__ float blo(unsigned int u) { return __uint_as_float(u << 16); }
static __device__ __forceinline__ float bhi(unsigned int u) { return __uint_as_float(u & 0xffff0000u); }
static __device__ __forceinline__ unsigned int pk2(float a, float b) {
    return (unsigned int)f2bu(a) | ((unsigned int)f2bu(b) << 16);
}

// async global->LDS, 16B per lane; LDS base must be wave-uniform (HW adds lane*16)
typedef __attribute__((address_space(1))) const void ga_void;
typedef __attribute__((address_space(3))) void lds_void;
static __device__ __forceinline__ void async16(const void* g, void* l) {
    __builtin_amdgcn_global_load_lds((ga_void*)g, (lds_void*)l, 16, 0, 0);
}

// ---------------- weight transpose f32 -> bf16 (+K padding with zeros) ------
__global__ void transpose_pad(const float* __restrict__ W, int K, int Nd,
                              unsigned short* __restrict__ Wt, int Kpad) {
    int t = blockIdx.x * 256 + threadIdx.x;
    if (t >= Nd * Kpad) return;
    int n = t / Kpad, k = t - n * Kpad;
    Wt[t] = (k < K) ? f2bu(W[(size_t)k * Nd + n]) : (unsigned short)0;
}

// ---------------- CSR build ----------------
__global__ void edge_hist(const int* __restrict__ dst, int* __restrict__ deg) {
    int e = blockIdx.x * 256 + threadIdx.x;
    if (e < E_EDGES) atomicAdd(&deg[dst[e]], 1);
}

__global__ void scan_kernel(const int* __restrict__ deg, int N,
                            int* __restrict__ row_start, int* __restrict__ cursor) {
    __shared__ int sh[1024];
    int t = threadIdx.x;
    int chunk = (N + 1023) >> 10;
    int lo = t * chunk;
    int hi = lo + chunk; if (hi > N) hi = N;
    if (lo > N) lo = N;
    int s = 0;
    for (int i = lo; i < hi; i++) s += deg[i];
    sh[t] = s;
    __syncthreads();
    for (int off = 1; off < 1024; off <<= 1) {
        int v = (t >= off) ? sh[t - off] : 0;
        __syncthreads();
        sh[t] += v;
        __syncthreads();
    }
    int run = (t == 0) ? 0 : sh[t - 1];
    for (int i = lo; i < hi; i++) {
        row_start[i] = run; cursor[i] = run; run += deg[i];
    }
    if (t == 1023) row_start[N] = run;
}

__global__ void edge_scatter(const int* __restrict__ src, const int* __restrict__ dst,
                             int* __restrict__ cursor, int* __restrict__ csr_src) {
    int e = blockIdx.x * 256 + threadIdx.x;
    if (e < E_EDGES) {
        int p = atomicAdd(&cursor[dst[e]], 1);
        if (p >= 0 && p < E_EDGES) csr_src[p] = src[e];
    }
}

// ---------------- fused CSR aggregation, bf16 in / bf16 out, f32 accumulate
// One wave per node; full row in registers; shfl-broadcast indices; edges in
// groups of 8 (8 wide loads in flight). +bias/LN/relu options fused.
template <int D, int DOUT, int DO_LN>
__global__ void csr_agg_ln_h(const unsigned short* __restrict__ X,
                             const int* __restrict__ row_start,
                             const int* __restrict__ csr_src,
                             const float* __restrict__ bias,
                             unsigned short* __restrict__ Y,
                             int addCenter, int doRelu) {
    constexpr int VE = (D % 512 == 0) ? 8 : 2;
    constexpr int R = (D + 64 * VE - 1) / (64 * VE);
    static_assert(VE == 2 || R == 1, "VE8 path assumes single round");
    static_assert(!DO_LN || (D % (64 * VE) == 0), "LN path needs full lanes");
    constexpr int U = D / 2;
    constexpr int UO = DOUT / 2;
    static_assert(D % 2 == 0 && DOUT % 2 == 0, "even dims");

    int node = blockIdx.x * 4 + (threadIdx.x >> 6);
    if (node >= N_NODES) return;
    int lane = threadIdx.x & 63;

    float acc[R][VE];
#pragma unroll
    for (int r = 0; r < R; r++)
#pragma unroll
        for (int i = 0; i < VE; i++) acc[r][i] = 0.0f;

    int s0 = row_start[node], s1 = row_start[node + 1];
    if (s0 < 0) s0 = 0;
    if (s1 > E_EDGES) s1 = E_EDGES;

    if constexpr (VE == 8) {
        auto add_u4 = [&](uint4 u) {
            acc[0][0] += blo(u.x); acc[0][1] += bhi(u.x);
            acc[0][2] += blo(u.y); acc[0][3] += bhi(u.y);
            acc[0][4] += blo(u.z); acc[0][5] += bhi(u.z);
            acc[0][6] += blo(u.w); acc[0][7] += bhi(u.w);
        };
        if (addCenter)
            add_u4(*reinterpret_cast<const uint4*>(X + (size_t)node * D + lane * 8));
        for (int j0 = s0; j0 < s1; j0 += 64) {
            int cnt = s1 - j0; if (cnt > 64) cnt = 64;
            int myi = (lane < cnt) ? csr_src[j0 + lane] : 0;
            int t = 0;
            for (; t + 8 <= cnt; t += 8) {
                uint4 raw[8];
#pragma unroll
                for (int g = 0; g < 8; g++) {
                    int s = __shfl(myi, t + g);
                    if ((unsigned)s >= (unsigned)N_NODES) s = 0;
                    raw[g] = *reinterpret_cast<const uint4*>(X + (size_t)s * D + lane * 8);
                }
#pragma unroll
                for (int g = 0; g < 8; g++) add_u4(raw[g]);
            }
            for (; t < cnt; t++) {
                int s = __shfl(myi, t);
                if ((unsigned)s >= (unsigned)N_NODES) s = 0;
                add_u4(*reinterpret_cast<const uint4*>(X + (size_t)s * D + lane * 8));
            }
        }
        if (bias) {
            const float4* bp = reinterpret_cast<const float4*>(bias + lane * 8);
            float4 b0 = bp[0], b1 = bp[1];
            acc[0][0] += b0.x; acc[0][1] += b0.y; acc[0][2] += b0.z; acc[0][3] += b0.w;
            acc[0][4] += b1.x; acc[0][5] += b1.y; acc[0][6] += b1.z; acc[0][7] += b1.w;
        }
    } else {
        auto add_u = [&](int r, unsigned int u) { acc[r][0] += blo(u); acc[r][1] += bhi(u); };
        if (addCenter) {
#pragma unroll
            for (int r = 0; r < R; r++) {
                int unit = r * 64 + lane;
                if (unit < U)
                    add_u(r, *reinterpret_cast<const unsigned int*>(X + (size_t)node * D + unit * 2));
            }
        }
        for (int j0 = s0; j0 < s1; j0 += 64) {
            int cnt = s1 - j0; if (cnt > 64) cnt = 64;
            int myi = (lane < cnt) ? csr_src[j0 + lane] : 0;
            int t = 0;
            for (; t + 8 <= cnt; t += 8) {
                unsigned int raw[8][R];
#pragma unroll
                for (int g = 0; g < 8; g++) {
                    int s = __shfl(myi, t + g);
                    if ((unsigned)s >= (unsigned)N_NODES) s = 0;
#pragma unroll
                    for (int r = 0; r < R; r++) {
                        int unit = r * 64 + lane;
                        raw[g][r] = (unit < U)
                            ? *reinterpret_cast<const unsigned int*>(X + (size_t)s * D + unit * 2)
                            : 0u;
                    }
                }
#pragma unroll
                for (int g = 0; g < 8; g++)
#pragma unroll
                    for (int r = 0; r < R; r++) add_u(r, raw[g][r]);
            }
            for (; t < cnt; t++) {
                int s = __shfl(myi, t);
                if ((unsigned)s >= (unsigned)N_NODES) s = 0;
#pragma unroll
                for (int r = 0; r < R; r++) {
                    int unit = r * 64 + lane;
                    if (unit < U)
                        add_u(r, *reinterpret_cast<const unsigned int*>(X + (size_t)s * D + unit * 2));
                }
            }
        }
        if (bias) {
#pragma unroll
            for (int r = 0; r < R; r++) {
                int unit = r * 64 + lane;
                if (unit < U) { acc[r][0] += bias[unit * 2]; acc[r][1] += bias[unit * 2 + 1]; }
            }
        }
    }

    if constexpr (DO_LN) {
        float s = 0.0f;
#pragma unroll
        for (int r = 0; r < R; r++)
#pragma unroll
            for (int i = 0; i < VE; i++) s += acc[r][i];
        for (int o = 32; o; o >>= 1) s += __shfl_xor(s, o);
        float mean = s * (1.0f / (float)D);
        float q = 0.0f;
#pragma unroll
        for (int r = 0; r < R; r++)
#pragma unroll
            for (int i = 0; i < VE; i++) { float d = acc[r][i] - mean; q += d * d; }
        for (int o = 32; o; o >>= 1) q += __shfl_xor(q, o);
        float rs_ = rsqrtf(q * (1.0f / (float)D) + 1e-5f);
#pragma unroll
        for (int r = 0; r < R; r++)
#pragma unroll
            for (int i = 0; i < VE; i++) acc[r][i] = (acc[r][i] - mean) * rs_;
    }

    if (doRelu) {
#pragma unroll
        for (int r = 0; r < R; r++)
#pragma unroll
            for (int i = 0; i < VE; i++) if (acc[r][i] < 0.0f) acc[r][i] = 0.0f;
    }

    if constexpr (VE == 8) {
        uint4 o = make_uint4(pk2(acc[0][0], acc[0][1]), pk2(acc[0][2], acc[0][3]),
                             pk2(acc[0][4], acc[0][5]), pk2(acc[0][6], acc[0][7]));
        *reinterpret_cast<uint4*>(Y + (size_t)node * DOUT + lane * 8) = o;
    } else {
        constexpr int RO = (UO + 63) / 64;
#pragma unroll
        for (int r = 0; r < RO; r++) {
            int unit = r * 64 + lane;
            if (unit < UO) {
                unsigned int v = 0u;
                if (r < R && unit < U) v = pk2(acc[r][0], acc[r][1]);
                *reinterpret_cast<unsigned int*>(Y + (size_t)node * DOUT + unit * 2) = v;
            }
        }
    }
}

// ---------------- LayerNorm(+bias)+relu over 512-wide bf16 rows, in-place safe
__global__ void ln_relu_h512(const unsigned short* __restrict__ Yin,
                             const float* __restrict__ bias,
                             unsigned short* __restrict__ Out) {
    int row = blockIdx.x * 4 + (threadIdx.x >> 6);
    if (row >= N_NODES) return;
    int lane = threadIdx.x & 63;
    uint4 u = *reinterpret_cast<const uint4*>(Yin + (size_t)row * 512 + lane * 8);
    const float4* bp = reinterpret_cast<const float4*>(bias + lane * 8);
    float4 b0 = bp[0], b1 = bp[1];
    float v[8];
    v[0] = blo(u.x) + b0.x; v[1] = bhi(u.x) + b0.y;
    v[2] = blo(u.y) + b0.z; v[3] = bhi(u.y) + b0.w;
    v[4] = blo(u.z) + b1.x; v[5] = bhi(u.z) + b1.y;
    v[6] = blo(u.w) + b1.z; v[7] = bhi(u.w) + b1.w;
    float s = 0.0f;
#pragma unroll
    for (int i = 0; i < 8; i++) s += v[i];
    for (int o = 32; o; o >>= 1) s += __shfl_xor(s, o);
    float mean = s * (1.0f / 512.0f);
    float q = 0.0f;
#pragma unroll
    for (int i = 0; i < 8; i++) { float d = v[i] - mean; q += d * d; }
    for (int o = 32; o; o >>= 1) q += __shfl_xor(q, o);
    float rs = rsqrtf(q * (1.0f / 512.0f) + 1e-5f);
#pragma unroll
    for (int i = 0; i < 8; i++) {
        float o = (v[i] - mean) * rs;
        v[i] = o > 0.0f ? o : 0.0f;
    }
    uint4 o = make_uint4(pk2(v[0], v[1]), pk2(v[2], v[3]), pk2(v[4], v[5]), pk2(v[6], v[7]));
    *reinterpret_cast<uint4*>(Out + (size_t)row * 512 + lane * 8) = o;
}

// ---------------- MFMA GEMM: C[M,Nd] = A[M,K] * Bt[Nd,K]^T (+bias)
// BM=128, BN=BLKN (128: 4 waves/256thr, 256: 8 waves/512thr), BK=64.
// B (and A when bf16) staged via global_load_lds(16B) into linear LDS with
// XOR-16B-slot swizzle (source-side pre-swizzle + matching read swizzle) so
// the stride-128B fragment ds_read_b128 stays ~conflict-free. f32 A staged
// via VALU RNE-pack into padded (stride-72) LDS.
// Grid: 1D, lid%8 = bm%8 (XCD-affine: all bn for a given bm land on one XCD's
// L2 -> A re-fetch absorbed), bn varies fastest. grid.x = 240*nbn.
template <int ABF, int CBF, int BLKN>
__global__ __launch_bounds__(BLKN * 2, 2) void gemm_bt(
    const void* __restrict__ A_, int lda, const unsigned short* __restrict__ Bt,
    int M, int K, void* __restrict__ C_, int ldc, const float* __restrict__ bias,
    int nbn) {
    constexpr int THREADS = BLKN * 2;
    constexpr int NW = THREADS / 64;
    constexpr int WNC = BLKN / 64;      // waves along N
    constexpr int ASTR = ABF ? 64 : 72; // LDS row stride (shorts)
    __shared__ __align__(16) unsigned short As[128 * ASTR];
    __shared__ __align__(16) unsigned short Bs[BLKN * 64];

    // XCD-affine decode (bijective over 240*nbn; bm>=235 blocks exit)
    int lid = blockIdx.x;
    int bmlow = lid & 7;
    int t2 = lid >> 3;
    int bmh = t2 / nbn;
    int bn = t2 - bmh * nbn;
    int bm = bmh * 8 + bmlow;
    if (bm * 128 >= M) return;

    const int t = threadIdx.x;
    const int lane = t & 63;
    const int wave = t >> 6;
    const int wm = wave / WNC, wn = wave % WNC;
    const int quad = lane >> 4, m16 = lane & 15;

    floatx4 acc[4][4];
#pragma unroll
    for (int i = 0; i < 4; i++)
#pragma unroll
        for (int j = 0; j < 4; j++)
#pragma unroll
            for (int r = 0; r < 4; r++) acc[i][j][r] = 0.0f;

    union Pk { unsigned short h[8]; uint4 v; };
    const int l8 = lane >> 3;            // sub-row within 8-row group
    const int gseg = (lane & 7) ^ l8;    // pre-swizzled 16B slot in source

    for (int k0 = 0; k0 < K; k0 += 64) {
        if constexpr (ABF) {
            // A: async 16B/lane, 8 rows per wave-call, swizzled source slot
            constexpr int ACALLS = 128 / (NW * 8);
#pragma unroll
            for (int i = 0; i < ACALLS; i++) {
                int rb = (i * NW + wave) * 8;
                const unsigned short* gp = (const unsigned short*)A_ +
                    (size_t)(bm * 128 + rb + l8) * lda + k0 + gseg * 8;
                async16(gp, &As[rb * 64]);
            }
        } else {
            // A: f32 -> bf16 RNE pack into padded LDS
            constexpr int GR = 1024 / THREADS;
#pragma unroll
            for (int i = 0; i < GR; i++) {
                int q = i * THREADS + t;
                int r = q >> 3, g = q & 7;
                int grow = bm * 128 + r;
                uint4 val = make_uint4(0u, 0u, 0u, 0u);
                if (grow < M) {
                    const float* ap = (const float*)A_ + (size_t)grow * lda + k0 + g * 8;
                    float4 f0 = *reinterpret_cast<const float4*>(ap);
                    float4 f1 = *reinterpret_cast<const float4*>(ap + 4);
                    Pk pk;
                    pk.h[0] = f2bu(f0.x); pk.h[1] = f2bu(f0.y);
                    pk.h[2] = f2bu(f0.z); pk.h[3] = f2bu(f0.w);
                    pk.h[4] = f2bu(f1.x); pk.h[5] = f2bu(f1.y);
                    pk.h[6] = f2bu(f1.z); pk.h[7] = f2bu(f1.w);
                    val = pk.v;
                }
                *reinterpret_cast<uint4*>(&As[r * 72 + g * 8]) = val;
            }
        }
        // B: async 16B/lane, swizzled source slot (rows always in range)
        constexpr int BCALLS = BLKN / (NW * 8);
#pragma unroll
        for (int i = 0; i < BCALLS; i++) {
            int rb = (i * NW + wave) * 8;
            const unsigned short* gp = Bt + (size_t)(bn * BLKN + rb + l8) * K + k0 + gseg * 8;
            async16(gp, &Bs[rb * 64]);
        }
        __syncthreads();
#pragma unroll
        for (int kk = 0; kk < 2; kk++) {
            bf16x8 af[4], bfr[4];
#pragma unroll
            for (int i = 0; i < 4; i++) {
                int r = wm * 64 + i * 16 + m16;
                int off;
                if constexpr (ABF) off = r * 64 + (((kk * 4 + quad) ^ (r & 7)) * 8);
                else off = r * 72 + (kk * 4 + quad) * 8;
                af[i] = *reinterpret_cast<const bf16x8*>(&As[off]);
            }
#pragma unroll
            for (int j = 0; j < 4; j++) {
                int r = wn * 64 + j * 16 + m16;
                bfr[j] = *reinterpret_cast<const bf16x8*>(&Bs[r * 64 + (((kk * 4 + quad) ^ (r & 7)) * 8)]);
            }
#pragma unroll
            for (int i = 0; i < 4; i++)
#pragma unroll
                for (int j = 0; j < 4; j++)
                    acc[i][j] = __builtin_amdgcn_mfma_f32_16x16x32_bf16(af[i], bfr[j], acc[i][j], 0, 0, 0);
        }
        __syncthreads();
    }
    // epilogue: C/D layout col=lane&15, row=quad*4+reg (m89-verified)
#pragma unroll
    for (int i = 0; i < 4; i++) {
        int r0 = bm * 128 + wm * 64 + i * 16 + quad * 4;
#pragma unroll
        for (int j = 0; j < 4; j++) {
            int c = bn * BLKN + wn * 64 + j * 16 + m16;
            float bia = bias ? bias[c] : 0.0f;
#pragma unroll
            for (int r = 0; r < 4; r++) {
                int row = r0 + r;
                if (row < M) {
                    float val = acc[i][j][r] + bia;
                    if constexpr (CBF)
                        ((unsigned short*)C_)[(size_t)row * ldc + c] = f2bu(val);
                    else
                        ((float*)C_)[(size_t)row * ldc + c] = val;
                }
            }
        }
    }
}

// ---------------- subgraph mean pool: zn bf16 [N,128] -> out f32 [N,128]
__global__ void pool_kernel_h(const unsigned short* __restrict__ zn, const int* __restrict__ idx,
                              float* __restrict__ out) {
    int i = blockIdx.x * 4 + (threadIdx.x >> 6);
    if (i >= N_NODES) return;
    int lane = threadIdx.x & 63;
    int myi = (lane < KSUB) ? idx[i * KSUB + lane] : 0;
    float ax = 0.0f, ay = 0.0f;
#pragma unroll
    for (int t = 0; t < KSUB; t++) {
        int s = __shfl(myi, t);
        if ((unsigned)s >= (unsigned)N_NODES) s = 0;
        unsigned int u = *reinterpret_cast<const unsigned int*>(zn + (size_t)s * 128 + lane * 2);
        ax += blo(u); ay += bhi(u);
    }
    *reinterpret_cast<float2*>(out + (size_t)i * 128 + lane * 2) =
        make_float2(ax * (1.0f / KSUB), ay * (1.0f / KSUB));
}

// ---------------- batch embedding MLP (f32): [N,8] -> relu 12 -> 16
__global__ void batch_emb_kernel(const float* __restrict__ bl, const float* __restrict__ W0,
                                 const float* __restrict__ b0, const float* __restrict__ W1,
                                 const float* __restrict__ b1, float* __restrict__ out) {
    int i = blockIdx.x * 256 + threadIdx.x;
    if (i >= N_NODES) return;
    float in[8];
#pragma unroll
    for (int d = 0; d < 8; d++) in[d] = bl[(size_t)i * 8 + d];
    float h[12];
#pragma unroll
    for (int j = 0; j < 12; j++) {
        float a = b0[j];
#pragma unroll
        for (int d = 0; d < 8; d++) a += in[d] * W0[d * 12 + j];
        h[j] = a > 0.0f ? a : 0.0f;
    }
#pragma unroll
    for (int j = 0; j < 16; j++) {
        float a = b1[j];
#pragma unroll
        for (int k = 0; k < 12; k++) a += h[k] * W1[k * 16 + j];
        out[(size_t)i * 16 + j] = a;
    }
}

// ---------------- concat zn bf16[128] ++ bemb f32[16] -> znb bf16[144]
__global__ void concat_kernel_h(const unsigned short* __restrict__ zn,
                                const float* __restrict__ be,
                                unsigned short* __restrict__ znb) {
    int i = blockIdx.x;
    int t = threadIdx.x;  // 192
    if (t < 128) znb[(size_t)i * 144 + t] = zn[(size_t)i * 128 + t];
    else if (t < 144) znb[(size_t)i * 144 + t] = f2bu(be[(size_t)i * 16 + (t - 128)]);
}

// ---------------- bilinear discriminator, phase 2: gathered row dots (f32)
__global__ void bilinear_dot(const float* __restrict__ U, const float* __restrict__ z_shf,
                             const int* __restrict__ pos, const int* __restrict__ neg,
                             float* __restrict__ out_pos, float* __restrict__ out_neg) {
    int p = blockIdx.x * 4 + (threadIdx.x >> 6);
    if (p >= NPAIR) return;
    int lane = threadIdx.x & 63;
    int ip = pos[p], in_ = neg[p];
    if ((unsigned)ip >= (unsigned)N_NODES) ip = 0;
    if ((unsigned)in_ >= (unsigned)N_NODES) in_ = 0;
    float2 u = *reinterpret_cast<const float2*>(U + (size_t)ip * 128 + lane * 2);
    float2 zp = *reinterpret_cast<const float2*>(z_shf + (size_t)ip * 128 + lane * 2);
    float2 zn = *reinterpret_cast<const float2*>(z_shf + (size_t)in_ * 128 + lane * 2);
    float vp = u.x * zp.x + u.y * zp.y;
    float vn = u.x * zn.x + u.y * zn.y;
    for (int o = 32; o; o >>= 1) { vp += __shfl_xor(vp, o); vn += __shfl_xor(vn, o); }
    if (lane == 0) { out_pos[p] = vp; out_neg[p] = vn; }
}

// ---------------- batch discriminator MLP (f32): [N,128] -> relu 64 -> 8
__global__ void bd_kernel(const float* __restrict__ z_sub, const float* __restrict__ W0,
                          const float* __restrict__ b0, const float* __restrict__ W1,
                          const float* __restrict__ b1, float* __restrict__ out) {
    __shared__ float zsh[4][128];
    __shared__ float hsh[4][64];
    int w = threadIdx.x >> 6, lane = threadIdx.x & 63;
    int node = blockIdx.x * 4 + w;
    zsh[w][lane] = z_sub[(size_t)node * 128 + lane];
    zsh[w][64 + lane] = z_sub[(size_t)node * 128 + 64 + lane];
    __syncthreads();
    float h = b0[lane];
    for (int d = 0; d < 128; d++) h += zsh[w][d] * W0[d * 64 + lane];
    if (h < 0.0f) h = 0.0f;
    hsh[w][lane] = h;
    __syncthreads();
    if (lane < 8) {
        float o = b1[lane];
        for (int l = 0; l < 64; l++) o += hsh[w][l] * W1[l * 8 + lane];
        out[(size_t)node * 8 + lane] = o;
    }
}

extern "C" void kernel_launch(void* const* d_in, const int* in_sizes, int n_in,
                              void* d_out, int out_size, void* d_ws, size_t ws_size,
                              hipStream_t stream) {
    const float* x = (const float*)d_in[0];
    const float* x_shf = (const float*)d_in[1];
    const float* blab = (const float*)d_in[2];
    const float* encW0 = (const float*)d_in[3];
    const float* encb0 = (const float*)d_in[4];
    const float* encW1 = (const float*)d_in[5];
    const float* encb1 = (const float*)d_in[6];
    const float* decW0 = (const float*)d_in[7];
    const float* decb0 = (const float*)d_in[8];
    const float* decW1 = (const float*)d_in[9];
    const float* decb1 = (const float*)d_in[10];
    const float* beW0 = (const float*)d_in[11];
    const float* beb0 = (const float*)d_in[12];
    const float* beW1 = (const float*)d_in[13];
    const float* beb1 = (const float*)d_in[14];
    const float* bdW0 = (const float*)d_in[15];
    const float* bdb0 = (const float*)d_in[16];
    const float* bdW1 = (const float*)d_in[17];
    const float* bdb1 = (const float*)d_in[18];
    const float* bilW = (const float*)d_in[19];
    const int* eidx = (const int*)d_in[20];
    const int* subidx = (const int*)d_in[21];
    const int* posi = (const int*)d_in[22];
    const int* negi = (const int*)d_in[23];
    float* out = (float*)d_out;

    char* ws = (char*)d_ws;
    size_t off = 0;
    auto alloc = [&](size_t bytes) -> void* {
        void* p = ws + off;
        off += (bytes + 255) & ~(size_t)255;
        return p;
    };
    unsigned short* encW0t = (unsigned short*)alloc((size_t)512 * 1024 * 2);
    unsigned short* encW1t = (unsigned short*)alloc((size_t)128 * 512 * 2);
    unsigned short* decW0t = (unsigned short*)alloc((size_t)512 * 192 * 2);
    unsigned short* decW1t = (unsigned short*)alloc((size_t)1024 * 512 * 2);
    unsigned short* bilWt = (unsigned short*)alloc((size_t)128 * 128 * 2);
    int* deg = (int*)alloc((size_t)N_NODES * 4);
    int* row_start = (int*)alloc((size_t)(N_NODES + 1) * 4);
    int* cursor = (int*)alloc((size_t)N_NODES * 4);
    int* csr_src = (int*)alloc((size_t)E_EDGES * 4);
    unsigned short* y0h = (unsigned short*)alloc((size_t)N_NODES * 512 * 2);   // enc/dec pre-act
    unsigned short* agg0h = (unsigned short*)alloc((size_t)N_NODES * 512 * 2); // enc h1; dec agg
    unsigned short* y1h = (unsigned short*)alloc((size_t)N_NODES * 128 * 2);   // enc layer-2 pre
    unsigned short* znh = (unsigned short*)alloc((size_t)N_NODES * 128 * 2);   // z_node (pass 0)
    unsigned short* znsh = (unsigned short*)alloc((size_t)N_NODES * 128 * 2);  // z_node shf
    unsigned short* znbh = (unsigned short*)alloc((size_t)N_NODES * 144 * 2);  // concat
    unsigned short* s1h = (unsigned short*)alloc((size_t)N_NODES * 192 * 2);   // dec agg1 (K-pad)
    float* bembf = (float*)alloc((size_t)N_NODES * 16 * 4);
    float* Ubil = (float*)alloc((size_t)N_NODES * 128 * 4);
    alloc(262144);  // tail pad: OOB-row async reads from last buffers stay in-workspace
    if (off > ws_size) return;  // workspace too small: fail cleanly

    const int* e_src = eidx;
    const int* e_dst = eidx + E_EDGES;

    // weight transposes f32 -> bf16 (pad K to multiple of 64 where needed)
    transpose_pad<<<(512 * 1024 + 255) / 256, 256, 0, stream>>>(encW0, 1024, 512, encW0t, 1024);
    transpose_pad<<<(128 * 512 + 255) / 256, 256, 0, stream>>>(encW1, 512, 128, encW1t, 512);
    transpose_pad<<<(512 * 192 + 255) / 256, 256, 0, stream>>>(decW0, 144, 512, decW0t, 192);
    transpose_pad<<<(1024 * 512 + 255) / 256, 256, 0, stream>>>(decW1, 512, 1024, decW1t, 512);
    transpose_pad<<<(128 * 128 + 255) / 256, 256, 0, stream>>>(bilW, 128, 128, bilWt, 128);

    // CSR build (keyed by dst, storing src)
    hipMemsetAsync(deg, 0, (size_t)N_NODES * 4, stream);
    edge_hist<<<E_EDGES / 256, 256, 0, stream>>>(e_dst, deg);
    scan_kernel<<<1, 1024, 0, stream>>>(deg, N_NODES, row_start, cursor);
    edge_scatter<<<E_EDGES / 256, 256, 0, stream>>>(e_src, e_dst, cursor, csr_src);

    // encoder, twice (x then x_shf); matmul-first so aggregation runs in the smaller dim.
    for (int pass = 0; pass < 2; pass++) {
        const float* xin = pass ? x_shf : x;
        unsigned short* zn = pass ? znsh : znh;
        float* zsub_out = out + (pass ? 3840000 : 0);
        gemm_bt<0, 1, 256><<<480, 512, 0, stream>>>(xin, 1024, encW0t, N_NODES, 1024, y0h, 512, nullptr, 2);
        csr_agg_ln_h<512, 512, 1><<<7500, 256, 0, stream>>>(y0h, row_start, csr_src, encb0, agg0h, 1, 1);
        gemm_bt<1, 1, 128><<<240, 256, 0, stream>>>(agg0h, 512, encW1t, N_NODES, 512, y1h, 128, nullptr, 1);
        csr_agg_ln_h<128, 128, 1><<<7500, 256, 0, stream>>>(y1h, row_start, csr_src, encb1, zn, 1, 1);
        pool_kernel_h<<<7500, 256, 0, stream>>>(zn, subidx, zsub_out);
    }

    // batch embedding + concat
    batch_emb_kernel<<<(N_NODES + 255) / 256, 256, 0, stream>>>(blab, beW0, beb0, beW1, beb1, bembf);
    concat_kernel_h<<<30000, 192, 0, stream>>>(znh, bembf, znbh);

    // decoder (agg-first so aggregation runs in the smaller dim)
    csr_agg_ln_h<144, 192, 0><<<7500, 256, 0, stream>>>(znbh, row_start, csr_src, nullptr, s1h, 1, 0);
    gemm_bt<1, 1, 256><<<480, 512, 0, stream>>>(s1h, 192, decW0t, N_NODES, 192, y0h, 512, nullptr, 2);
    ln_relu_h512<<<7500, 256, 0, stream>>>(y0h, decb0, y0h);  // in-place
    csr_agg_ln_h<512, 512, 0><<<7500, 256, 0, stream>>>(y0h, row_start, csr_src, nullptr, agg0h, 1, 0);
    gemm_bt<1, 0, 256><<<960, 512, 0, stream>>>(agg0h, 512, decW1t, N_NODES, 512, out + 7680000, 1024, decb1, 4);

    // heads: bilinear via U = z_sub @ bil_W
    gemm_bt<0, 0, 128><<<240, 256, 0, stream>>>(out, 128, bilWt, N_NODES, 128, Ubil, 128, nullptr, 1);
    bilinear_dot<<<(NPAIR + 3) / 4, 256, 0, stream>>>(Ubil, out + 3840000, posi, negi,
                                                      out + 38400000, out + 38416384);
    bd_kernel<<<7500, 256, 0, stream>>>(out, bdW0, bdb0, bdW1, bdb1, out + 38432768);
}

// Round 4
// 1014.514 us; speedup vs baseline: 2.4340x; 1.0450x over previous
//
#include <hip/hip_runtime.h>
#include <hip/hip_bf16.h>

#define N_NODES 30000
#define E_EDGES 480000
#define KSUB 32
#define NPAIR 16384

typedef __hip_bfloat16 bf16;
typedef __bf16 bf16x8 __attribute__((ext_vector_type(8)));
typedef float floatx4 __attribute__((ext_vector_type(4)));

static __device__ __forceinline__ unsigned short f2bu(float f) {
    // round-to-nearest-even f32 -> bf16 (finite inputs only)
    unsigned int u = __float_as_uint(f);
    unsigned int r = (u + 0x7fffu + ((u >> 16) & 1u)) >> 16;
    return (unsigned short)r;
}
static __device__ __forceinline__ float blo(unsigned int u) { return __uint_as_float(u << 16); }
static __device__ __forceinline__ float bhi(unsigned int u) { return __uint_as_float(u & 0xffff0000u); }
static __device__ __forceinline__ unsigned int pk2(float a, float b) {
    return (unsigned int)f2bu(a) | ((unsigned int)f2bu(b) << 16);
}

// async global->LDS, 16B per lane; LDS base must be wave-uniform (HW adds lane*16)
typedef __attribute__((address_space(1))) const void ga_void;
typedef __attribute__((address_space(3))) void lds_void;
static __device__ __forceinline__ void async16(const void* g, void* l) {
    __builtin_amdgcn_global_load_lds((ga_void*)g, (lds_void*)l, 16, 0, 0);
}

// ---------------- all weight transposes f32 -> bf16, one launch ------------
// segments: encW0(1024x512->512x1024) encW1(512x128->128x512)
//           decW0(144x512->512x192)   decW1(512x1024->1024x512) bil(128x128)
__global__ void transpose_all(const float* __restrict__ encW0, const float* __restrict__ encW1,
                              const float* __restrict__ decW0, const float* __restrict__ decW1,
                              const float* __restrict__ bilW,
                              unsigned short* __restrict__ encW0t, unsigned short* __restrict__ encW1t,
                              unsigned short* __restrict__ decW0t, unsigned short* __restrict__ decW1t,
                              unsigned short* __restrict__ bilWt) {
    int t = blockIdx.x * 256 + threadIdx.x;
    const float* W; unsigned short* Wt; int K, Nd, Kpad, u;
    if (t < 524288) { W = encW0; Wt = encW0t; K = 1024; Nd = 512; Kpad = 1024; u = t; }
    else if (t < 589824) { W = encW1; Wt = encW1t; K = 512; Nd = 128; Kpad = 512; u = t - 524288; }
    else if (t < 688128) { W = decW0; Wt = decW0t; K = 144; Nd = 512; Kpad = 192; u = t - 589824; }
    else if (t < 1212416) { W = decW1; Wt = decW1t; K = 512; Nd = 1024; Kpad = 512; u = t - 688128; }
    else if (t < 1228800) { W = bilW; Wt = bilWt; K = 128; Nd = 128; Kpad = 128; u = t - 1212416; }
    else return;
    int n = u / Kpad, k = u - n * Kpad;
    Wt[u] = (k < K) ? f2bu(W[(size_t)k * Nd + n]) : (unsigned short)0;
}

// ---------------- CSR build ----------------
__global__ void edge_hist(const int* __restrict__ dst, int* __restrict__ deg) {
    int e = blockIdx.x * 256 + threadIdx.x;
    if (e < E_EDGES) atomicAdd(&deg[dst[e]], 1);
}

__global__ void scan_kernel(const int* __restrict__ deg, int N,
                            int* __restrict__ row_start, int* __restrict__ cursor) {
    __shared__ int sh[1024];
    int t = threadIdx.x;
    int chunk = (N + 1023) >> 10;
    int lo = t * chunk;
    int hi = lo + chunk; if (hi > N) hi = N;
    if (lo > N) lo = N;
    int s = 0;
    for (int i = lo; i < hi; i++) s += deg[i];
    sh[t] = s;
    __syncthreads();
    for (int off = 1; off < 1024; off <<= 1) {
        int v = (t >= off) ? sh[t - off] : 0;
        __syncthreads();
        sh[t] += v;
        __syncthreads();
    }
    int run = (t == 0) ? 0 : sh[t - 1];
    for (int i = lo; i < hi; i++) {
        row_start[i] = run; cursor[i] = run; run += deg[i];
    }
    if (t == 1023) row_start[N] = run;
}

__global__ void edge_scatter(const int* __restrict__ src, const int* __restrict__ dst,
                             int* __restrict__ cursor, int* __restrict__ csr_src) {
    int e = blockIdx.x * 256 + threadIdx.x;
    if (e < E_EDGES) {
        int p = atomicAdd(&cursor[dst[e]], 1);
        if (p >= 0 && p < E_EDGES) csr_src[p] = src[e];
    }
}

// ---------------- fused CSR aggregation, bf16 in / bf16 out, f32 accumulate
// Virtual-node batched over nv nodes: v<N_NODES uses Xa (node=v), else Xb
// (node=v-N_NODES); gathers stay pass-local. One wave per node, full row in
// registers, shfl-broadcast indices. VE8 (D=512): double-buffered 8-groups of
// uint4 loads (16 in flight). VE2 (D=128): 16-groups. +bias/LN/relu fused.
template <int D, int DOUT, int DO_LN>
__global__ __launch_bounds__(256, 4) void csr_agg_ln_h(
    const unsigned short* __restrict__ Xa, const unsigned short* __restrict__ Xb, int nv,
    const int* __restrict__ row_start, const int* __restrict__ csr_src,
    const float* __restrict__ bias, unsigned short* __restrict__ Y,
    int addCenter, int doRelu) {
    constexpr int VE = (D % 512 == 0) ? 8 : 2;
    constexpr int R = (D + 64 * VE - 1) / (64 * VE);
    static_assert(VE == 2 || R == 1, "VE8 path assumes single round");
    static_assert(D % (64 * VE) == 0 && D == DOUT, "paths need exact divisibility");

    int v = blockIdx.x * 4 + (threadIdx.x >> 6);
    if (v >= nv) return;
    int lane = threadIdx.x & 63;
    const unsigned short* X = (v < N_NODES) ? Xa : Xb;
    int node = (v < N_NODES) ? v : v - N_NODES;

    float acc[R][VE];
#pragma unroll
    for (int r = 0; r < R; r++)
#pragma unroll
        for (int i = 0; i < VE; i++) acc[r][i] = 0.0f;

    int s0 = row_start[node], s1 = row_start[node + 1];
    if (s0 < 0) s0 = 0;
    if (s1 > E_EDGES) s1 = E_EDGES;

    if constexpr (VE == 8) {
        auto add_u4 = [&](uint4 u) {
            acc[0][0] += blo(u.x); acc[0][1] += bhi(u.x);
            acc[0][2] += blo(u.y); acc[0][3] += bhi(u.y);
            acc[0][4] += blo(u.z); acc[0][5] += bhi(u.z);
            acc[0][6] += blo(u.w); acc[0][7] += bhi(u.w);
        };
        if (addCenter)
            add_u4(*reinterpret_cast<const uint4*>(X + (size_t)node * D + lane * 8));
        for (int j0 = s0; j0 < s1; j0 += 64) {
            int cnt = s1 - j0; if (cnt > 64) cnt = 64;
            int myi = (lane < cnt) ? csr_src[j0 + lane] : 0;
            uint4 rawA[8], rawB[8];
            auto issue8 = [&](uint4 (&raw)[8], int tb) {
#pragma unroll
                for (int g = 0; g < 8; g++) {
                    int s = __shfl(myi, (tb + g) & 63);
                    if ((unsigned)s >= (unsigned)N_NODES) s = 0;
                    raw[g] = *reinterpret_cast<const uint4*>(X + (size_t)s * D + lane * 8);
                }
            };
            auto consume8 = [&](uint4 (&raw)[8], int tb) {
#pragma unroll
                for (int g = 0; g < 8; g++)
                    if (tb + g < cnt) add_u4(raw[g]);
            };
            issue8(rawA, 0);
            int t = 0;
            while (true) {
                if (t + 8 < cnt) {
                    issue8(rawB, t + 8);
                    consume8(rawA, t);
                    if (t + 16 < cnt) {
                        issue8(rawA, t + 16);
                        consume8(rawB, t + 8);
                        t += 16;
                    } else { consume8(rawB, t + 8); break; }
                } else { consume8(rawA, t); break; }
            }
        }
        if (bias) {
            const float4* bp = reinterpret_cast<const float4*>(bias + lane * 8);
            float4 b0 = bp[0], b1 = bp[1];
            acc[0][0] += b0.x; acc[0][1] += b0.y; acc[0][2] += b0.z; acc[0][3] += b0.w;
            acc[0][4] += b1.x; acc[0][5] += b1.y; acc[0][6] += b1.z; acc[0][7] += b1.w;
        }
    } else {
        auto add_u = [&](int r, unsigned int u) { acc[r][0] += blo(u); acc[r][1] += bhi(u); };
        if (addCenter) {
#pragma unroll
            for (int r = 0; r < R; r++)
                add_u(r, *reinterpret_cast<const unsigned int*>(X + (size_t)node * D + (r * 64 + lane) * 2));
        }
        for (int j0 = s0; j0 < s1; j0 += 64) {
            int cnt = s1 - j0; if (cnt > 64) cnt = 64;
            int myi = (lane < cnt) ? csr_src[j0 + lane] : 0;
            for (int t = 0; t < cnt; t += 16) {
                unsigned int raw[16][R];
#pragma unroll
                for (int g = 0; g < 16; g++) {
                    int s = __shfl(myi, (t + g) & 63);
                    if ((unsigned)s >= (unsigned)N_NODES) s = 0;
#pragma unroll
                    for (int r = 0; r < R; r++)
                        raw[g][r] = *reinterpret_cast<const unsigned int*>(X + (size_t)s * D + (r * 64 + lane) * 2);
                }
#pragma unroll
                for (int g = 0; g < 16; g++)
                    if (t + g < cnt)
#pragma unroll
                        for (int r = 0; r < R; r++) add_u(r, raw[g][r]);
            }
        }
        if (bias) {
#pragma unroll
            for (int r = 0; r < R; r++) {
                int unit = r * 64 + lane;
                acc[r][0] += bias[unit * 2]; acc[r][1] += bias[unit * 2 + 1];
            }
        }
    }

    if constexpr (DO_LN) {
        float s = 0.0f;
#pragma unroll
        for (int r = 0; r < R; r++)
#pragma unroll
            for (int i = 0; i < VE; i++) s += acc[r][i];
        for (int o = 32; o; o >>= 1) s += __shfl_xor(s, o);
        float mean = s * (1.0f / (float)D);
        float q = 0.0f;
#pragma unroll
        for (int r = 0; r < R; r++)
#pragma unroll
            for (int i = 0; i < VE; i++) { float d = acc[r][i] - mean; q += d * d; }
        for (int o = 32; o; o >>= 1) q += __shfl_xor(q, o);
        float rs_ = rsqrtf(q * (1.0f / (float)D) + 1e-5f);
#pragma unroll
        for (int r = 0; r < R; r++)
#pragma unroll
            for (int i = 0; i < VE; i++) acc[r][i] = (acc[r][i] - mean) * rs_;
    }

    if (doRelu) {
#pragma unroll
        for (int r = 0; r < R; r++)
#pragma unroll
            for (int i = 0; i < VE; i++) if (acc[r][i] < 0.0f) acc[r][i] = 0.0f;
    }

    if constexpr (VE == 8) {
        uint4 o = make_uint4(pk2(acc[0][0], acc[0][1]), pk2(acc[0][2], acc[0][3]),
                             pk2(acc[0][4], acc[0][5]), pk2(acc[0][6], acc[0][7]));
        *reinterpret_cast<uint4*>(Y + (size_t)v * DOUT + lane * 8) = o;
    } else {
#pragma unroll
        for (int r = 0; r < R; r++)
            *reinterpret_cast<unsigned int*>(Y + (size_t)v * DOUT + (r * 64 + lane) * 2) =
                pk2(acc[r][0], acc[r][1]);
    }
}

// ---------------- decoder agg-1 with fused concat: gathers zn[128]++bemb[16]
// out row s1h[192] (cols 144..191 zero, K-padded). addCenter folded.
__global__ __launch_bounds__(256, 4) void csr_agg_dec(
    const unsigned short* __restrict__ zn, const float* __restrict__ be,
    const int* __restrict__ row_start, const int* __restrict__ csr_src,
    unsigned short* __restrict__ Y) {
    int node = blockIdx.x * 4 + (threadIdx.x >> 6);
    if (node >= N_NODES) return;
    int lane = threadIdx.x & 63;
    float az0 = 0.0f, az1 = 0.0f, ab0 = 0.0f, ab1 = 0.0f;
    // center term
    {
        unsigned int u = *reinterpret_cast<const unsigned int*>(zn + (size_t)node * 128 + lane * 2);
        az0 += blo(u); az1 += bhi(u);
        if (lane < 8) {
            float2 b = *reinterpret_cast<const float2*>(be + (size_t)node * 16 + lane * 2);
            ab0 += b.x; ab1 += b.y;
        }
    }
    int s0 = row_start[node], s1 = row_start[node + 1];
    if (s0 < 0) s0 = 0;
    if (s1 > E_EDGES) s1 = E_EDGES;
    for (int j0 = s0; j0 < s1; j0 += 64) {
        int cnt = s1 - j0; if (cnt > 64) cnt = 64;
        int myi = (lane < cnt) ? csr_src[j0 + lane] : 0;
        for (int t = 0; t < cnt; t += 8) {
            unsigned int rawZ[8]; float2 rawB[8];
            int sv[8];
#pragma unroll
            for (int g = 0; g < 8; g++) {
                int s = __shfl(myi, (t + g) & 63);
                if ((unsigned)s >= (unsigned)N_NODES) s = 0;
                sv[g] = s;
                rawZ[g] = *reinterpret_cast<const unsigned int*>(zn + (size_t)s * 128 + lane * 2);
            }
            if (lane < 8) {
#pragma unroll
                for (int g = 0; g < 8; g++)
                    rawB[g] = *reinterpret_cast<const float2*>(be + (size_t)sv[g] * 16 + lane * 2);
            }
#pragma unroll
            for (int g = 0; g < 8; g++) {
                if (t + g < cnt) {
                    az0 += blo(rawZ[g]); az1 += bhi(rawZ[g]);
                    if (lane < 8) { ab0 += rawB[g].x; ab1 += rawB[g].y; }
                }
            }
        }
    }
    unsigned int* yr = reinterpret_cast<unsigned int*>(Y + (size_t)node * 192);
    yr[lane] = pk2(az0, az1);
    if (lane < 32) yr[64 + lane] = (lane < 8) ? pk2(ab0, ab1) : 0u;
}

// ---------------- LayerNorm(+bias)+relu over 512-wide bf16 rows, in-place safe
__global__ void ln_relu_h512(const unsigned short* __restrict__ Yin,
                             const float* __restrict__ bias,
                             unsigned short* __restrict__ Out) {
    int row = blockIdx.x * 4 + (threadIdx.x >> 6);
    if (row >= N_NODES) return;
    int lane = threadIdx.x & 63;
    uint4 u = *reinterpret_cast<const uint4*>(Yin + (size_t)row * 512 + lane * 8);
    const float4* bp = reinterpret_cast<const float4*>(bias + lane * 8);
    float4 b0 = bp[0], b1 = bp[1];
    float v[8];
    v[0] = blo(u.x) + b0.x; v[1] = bhi(u.x) + b0.y;
    v[2] = blo(u.y) + b0.z; v[3] = bhi(u.y) + b0.w;
    v[4] = blo(u.z) + b1.x; v[5] = bhi(u.z) + b1.y;
    v[6] = blo(u.w) + b1.z; v[7] = bhi(u.w) + b1.w;
    float s = 0.0f;
#pragma unroll
    for (int i = 0; i < 8; i++) s += v[i];
    for (int o = 32; o; o >>= 1) s += __shfl_xor(s, o);
    float mean = s * (1.0f / 512.0f);
    float q = 0.0f;
#pragma unroll
    for (int i = 0; i < 8; i++) { float d = v[i] - mean; q += d * d; }
    for (int o = 32; o; o >>= 1) q += __shfl_xor(q, o);
    float rs = rsqrtf(q * (1.0f / 512.0f) + 1e-5f);
#pragma unroll
    for (int i = 0; i < 8; i++) {
        float o = (v[i] - mean) * rs;
        v[i] = o > 0.0f ? o : 0.0f;
    }
    uint4 o = make_uint4(pk2(v[0], v[1]), pk2(v[2], v[3]), pk2(v[4], v[5]), pk2(v[6], v[7]));
    *reinterpret_cast<uint4*>(Out + (size_t)row * 512 + lane * 8) = o;
}

// ---------------- MFMA GEMM: C[M,Nd] = A[M,K] * Bt[Nd,K]^T (+bias)
// BM=128, BN=BLKN, BK=64. B (and bf16 A) staged via global_load_lds(16B) with
// XOR-16B-slot swizzle (source-side pre-swizzle + matching read). f32 A staged
// via VALU RNE-pack into padded LDS. XCD-affine 1D grid decode.
template <int ABF, int CBF, int BLKN>
__global__ __launch_bounds__(BLKN * 2, 2) void gemm_bt(
    const void* __restrict__ A_, int lda, const unsigned short* __restrict__ Bt,
    int M, int K, void* __restrict__ C_, int ldc, const float* __restrict__ bias,
    int nbn) {
    constexpr int THREADS = BLKN * 2;
    constexpr int NW = THREADS / 64;
    constexpr int WNC = BLKN / 64;
    constexpr int ASTR = ABF ? 64 : 72;
    __shared__ __align__(16) unsigned short As[128 * ASTR];
    __shared__ __align__(16) unsigned short Bs[BLKN * 64];

    int lid = blockIdx.x;
    int bmlow = lid & 7;
    int t2 = lid >> 3;
    int bmh = t2 / nbn;
    int bn = t2 - bmh * nbn;
    int bm = bmh * 8 + bmlow;
    if (bm * 128 >= M) return;

    const int t = threadIdx.x;
    const int lane = t & 63;
    const int wave = t >> 6;
    const int wm = wave / WNC, wn = wave % WNC;
    const int quad = lane >> 4, m16 = lane & 15;

    floatx4 acc[4][4];
#pragma unroll
    for (int i = 0; i < 4; i++)
#pragma unroll
        for (int j = 0; j < 4; j++)
#pragma unroll
            for (int r = 0; r < 4; r++) acc[i][j][r] = 0.0f;

    union Pk { unsigned short h[8]; uint4 v; };
    const int l8 = lane >> 3;
    const int gseg = (lane & 7) ^ l8;

    for (int k0 = 0; k0 < K; k0 += 64) {
        if constexpr (ABF) {
            constexpr int ACALLS = 128 / (NW * 8);
#pragma unroll
            for (int i = 0; i < ACALLS; i++) {
                int rb = (i * NW + wave) * 8;
                const unsigned short* gp = (const unsigned short*)A_ +
                    (size_t)(bm * 128 + rb + l8) * lda + k0 + gseg * 8;
                async16(gp, &As[rb * 64]);
            }
        } else {
            constexpr int GR = 1024 / THREADS;
#pragma unroll
            for (int i = 0; i < GR; i++) {
                int q = i * THREADS + t;
                int r = q >> 3, g = q & 7;
                int grow = bm * 128 + r;
                uint4 val = make_uint4(0u, 0u, 0u, 0u);
                if (grow < M) {
                    const float* ap = (const float*)A_ + (size_t)grow * lda + k0 + g * 8;
                    float4 f0 = *reinterpret_cast<const float4*>(ap);
                    float4 f1 = *reinterpret_cast<const float4*>(ap + 4);
                    Pk pk;
                    pk.h[0] = f2bu(f0.x); pk.h[1] = f2bu(f0.y);
                    pk.h[2] = f2bu(f0.z); pk.h[3] = f2bu(f0.w);
                    pk.h[4] = f2bu(f1.x); pk.h[5] = f2bu(f1.y);
                    pk.h[6] = f2bu(f1.z); pk.h[7] = f2bu(f1.w);
                    val = pk.v;
                }
                *reinterpret_cast<uint4*>(&As[r * 72 + g * 8]) = val;
            }
        }
        constexpr int BCALLS = BLKN / (NW * 8);
#pragma unroll
        for (int i = 0; i < BCALLS; i++) {
            int rb = (i * NW + wave) * 8;
            const unsigned short* gp = Bt + (size_t)(bn * BLKN + rb + l8) * K + k0 + gseg * 8;
            async16(gp, &Bs[rb * 64]);
        }
        __syncthreads();
#pragma unroll
        for (int kk = 0; kk < 2; kk++) {
            bf16x8 af[4], bfr[4];
#pragma unroll
            for (int i = 0; i < 4; i++) {
                int r = wm * 64 + i * 16 + m16;
                int off;
                if constexpr (ABF) off = r * 64 + (((kk * 4 + quad) ^ (r & 7)) * 8);
                else off = r * 72 + (kk * 4 + quad) * 8;
                af[i] = *reinterpret_cast<const bf16x8*>(&As[off]);
            }
#pragma unroll
            for (int j = 0; j < 4; j++) {
                int r = wn * 64 + j * 16 + m16;
                bfr[j] = *reinterpret_cast<const bf16x8*>(&Bs[r * 64 + (((kk * 4 + quad) ^ (r & 7)) * 8)]);
            }
#pragma unroll
            for (int i = 0; i < 4; i++)
#pragma unroll
                for (int j = 0; j < 4; j++)
                    acc[i][j] = __builtin_amdgcn_mfma_f32_16x16x32_bf16(af[i], bfr[j], acc[i][j], 0, 0, 0);
        }
        __syncthreads();
    }
#pragma unroll
    for (int i = 0; i < 4; i++) {
        int r0 = bm * 128 + wm * 64 + i * 16 + quad * 4;
#pragma unroll
        for (int j = 0; j < 4; j++) {
            int c = bn * BLKN + wn * 64 + j * 16 + m16;
            float bia = bias ? bias[c] : 0.0f;
#pragma unroll
            for (int r = 0; r < 4; r++) {
                int row = r0 + r;
                if (row < M) {
                    float val = acc[i][j][r] + bia;
                    if constexpr (CBF)
                        ((unsigned short*)C_)[(size_t)row * ldc + c] = f2bu(val);
                    else
                        ((float*)C_)[(size_t)row * ldc + c] = val;
                }
            }
        }
    }
}

// ---------------- subgraph mean pool, both passes: zn bf16 [60000,128]
// v<30000: idx rows as-is -> out+v*128; else idx+30000 -> out+3840000+...
__global__ void pool_kernel_h(const unsigned short* __restrict__ zn, const int* __restrict__ idx,
                              float* __restrict__ out) {
    int v = blockIdx.x * 4 + (threadIdx.x >> 6);
    if (v >= 2 * N_NODES) return;
    int lane = threadIdx.x & 63;
    int pass = v >= N_NODES;
    int i = pass ? v - N_NODES : v;
    int roff = pass ? N_NODES : 0;
    int myi = (lane < KSUB) ? idx[i * KSUB + lane] : 0;
    float ax = 0.0f, ay = 0.0f;
#pragma unroll
    for (int t = 0; t < KSUB; t++) {
        int s = __shfl(myi, t);
        if ((unsigned)s >= (unsigned)N_NODES) s = 0;
        unsigned int u = *reinterpret_cast<const unsigned int*>(zn + (size_t)(s + roff) * 128 + lane * 2);
        ax += blo(u); ay += bhi(u);
    }
    float* op = out + (pass ? 3840000 : 0) + (size_t)i * 128 + lane * 2;
    *reinterpret_cast<float2*>(op) = make_float2(ax * (1.0f / KSUB), ay * (1.0f / KSUB));
}

// ---------------- batch embedding MLP (f32): [N,8] -> relu 12 -> 16
__global__ void batch_emb_kernel(const float* __restrict__ bl, const float* __restrict__ W0,
                                 const float* __restrict__ b0, const float* __restrict__ W1,
                                 const float* __restrict__ b1, float* __restrict__ out) {
    int i = blockIdx.x * 256 + threadIdx.x;
    if (i >= N_NODES) return;
    float in[8];
#pragma unroll
    for (int d = 0; d < 8; d++) in[d] = bl[(size_t)i * 8 + d];
    float h[12];
#pragma unroll
    for (int j = 0; j < 12; j++) {
        float a = b0[j];
#pragma unroll
        for (int d = 0; d < 8; d++) a += in[d] * W0[d * 12 + j];
        h[j] = a > 0.0f ? a : 0.0f;
    }
#pragma unroll
    for (int j = 0; j < 16; j++) {
        float a = b1[j];
#pragma unroll
        for (int k = 0; k < 12; k++) a += h[k] * W1[k * 16 + j];
        out[(size_t)i * 16 + j] = a;
    }
}

// ---------------- bilinear discriminator, phase 2: gathered row dots (f32)
__global__ void bilinear_dot(const float* __restrict__ U, const float* __restrict__ z_shf,
                             const int* __restrict__ pos, const int* __restrict__ neg,
                             float* __restrict__ out_pos, float* __restrict__ out_neg) {
    int p = blockIdx.x * 4 + (threadIdx.x >> 6);
    if (p >= NPAIR) return;
    int lane = threadIdx.x & 63;
    int ip = pos[p], in_ = neg[p];
    if ((unsigned)ip >= (unsigned)N_NODES) ip = 0;
    if ((unsigned)in_ >= (unsigned)N_NODES) in_ = 0;
    float2 u = *reinterpret_cast<const float2*>(U + (size_t)ip * 128 + lane * 2);
    float2 zp = *reinterpret_cast<const float2*>(z_shf + (size_t)ip * 128 + lane * 2);
    float2 zn = *reinterpret_cast<const float2*>(z_shf + (size_t)in_ * 128 + lane * 2);
    float vp = u.x * zp.x + u.y * zp.y;
    float vn = u.x * zn.x + u.y * zn.y;
    for (int o = 32; o; o >>= 1) { vp += __shfl_xor(vp, o); vn += __shfl_xor(vn, o); }
    if (lane == 0) { out_pos[p] = vp; out_neg[p] = vn; }
}

// ---------------- batch discriminator MLP (f32): [N,128] -> relu 64 -> 8
__global__ void bd_kernel(const float* __restrict__ z_sub, const float* __restrict__ W0,
                          const float* __restrict__ b0, const float* __restrict__ W1,
                          const float* __restrict__ b1, float* __restrict__ out) {
    __shared__ float zsh[4][128];
    __shared__ float hsh[4][64];
    int w = threadIdx.x >> 6, lane = threadIdx.x & 63;
    int node = blockIdx.x * 4 + w;
    zsh[w][lane] = z_sub[(size_t)node * 128 + lane];
    zsh[w][64 + lane] = z_sub[(size_t)node * 128 + 64 + lane];
    __syncthreads();
    float h = b0[lane];
    for (int d = 0; d < 128; d++) h += zsh[w][d] * W0[d * 64 + lane];
    if (h < 0.0f) h = 0.0f;
    hsh[w][lane] = h;
    __syncthreads();
    if (lane < 8) {
        float o = b1[lane];
        for (int l = 0; l < 64; l++) o += hsh[w][l] * W1[l * 8 + lane];
        out[(size_t)node * 8 + lane] = o;
    }
}

extern "C" void kernel_launch(void* const* d_in, const int* in_sizes, int n_in,
                              void* d_out, int out_size, void* d_ws, size_t ws_size,
                              hipStream_t stream) {
    const float* x = (const float*)d_in[0];
    const float* x_shf = (const float*)d_in[1];
    const float* blab = (const float*)d_in[2];
    const float* encW0 = (const float*)d_in[3];
    const float* encb0 = (const float*)d_in[4];
    const float* encW1 = (const float*)d_in[5];
    const float* encb1 = (const float*)d_in[6];
    const float* decW0 = (const float*)d_in[7];
    const float* decb0 = (const float*)d_in[8];
    const float* decW1 = (const float*)d_in[9];
    const float* decb1 = (const float*)d_in[10];
    const float* beW0 = (const float*)d_in[11];
    const float* beb0 = (const float*)d_in[12];
    const float* beW1 = (const float*)d_in[13];
    const float* beb1 = (const float*)d_in[14];
    const float* bdW0 = (const float*)d_in[15];
    const float* bdb0 = (const float*)d_in[16];
    const float* bdW1 = (const float*)d_in[17];
    const float* bdb1 = (const float*)d_in[18];
    const float* bilW = (const float*)d_in[19];
    const int* eidx = (const int*)d_in[20];
    const int* subidx = (const int*)d_in[21];
    const int* posi = (const int*)d_in[22];
    const int* negi = (const int*)d_in[23];
    float* out = (float*)d_out;

    char* ws = (char*)d_ws;
    size_t off = 0;
    auto alloc = [&](size_t bytes) -> void* {
        void* p = ws + off;
        off += (bytes + 255) & ~(size_t)255;
        return p;
    };
    unsigned short* encW0t = (unsigned short*)alloc((size_t)512 * 1024 * 2);
    unsigned short* encW1t = (unsigned short*)alloc((size_t)128 * 512 * 2);
    unsigned short* decW0t = (unsigned short*)alloc((size_t)512 * 192 * 2);
    unsigned short* decW1t = (unsigned short*)alloc((size_t)1024 * 512 * 2);
    unsigned short* bilWt = (unsigned short*)alloc((size_t)128 * 128 * 2);
    int* deg = (int*)alloc((size_t)N_NODES * 4);
    int* row_start = (int*)alloc((size_t)(N_NODES + 1) * 4);
    int* cursor = (int*)alloc((size_t)N_NODES * 4);
    int* csr_src = (int*)alloc((size_t)E_EDGES * 4);
    unsigned short* y0h = (unsigned short*)alloc((size_t)60000 * 512 * 2);   // both passes; dec pre-act
    unsigned short* agg0h = (unsigned short*)alloc((size_t)60000 * 512 * 2); // enc h1 both; dec agg
    unsigned short* y1h = (unsigned short*)alloc((size_t)60000 * 128 * 2);   // enc L2 pre, both
    unsigned short* znh = (unsigned short*)alloc((size_t)60000 * 128 * 2);   // z_node both passes
    unsigned short* s1h = (unsigned short*)alloc((size_t)N_NODES * 192 * 2); // dec agg1 (K-pad)
    float* bembf = (float*)alloc((size_t)N_NODES * 16 * 4);
    float* Ubil = (float*)alloc((size_t)N_NODES * 128 * 4);
    alloc(262144);  // tail pad: OOB-row async reads stay in-workspace
    if (off > ws_size) return;  // workspace too small: fail cleanly

    const int* e_src = eidx;
    const int* e_dst = eidx + E_EDGES;

    // all weight transposes, one launch
    transpose_all<<<4800, 256, 0, stream>>>(encW0, encW1, decW0, decW1, bilW,
                                            encW0t, encW1t, decW0t, decW1t, bilWt);

    // CSR build (keyed by dst, storing src)
    hipMemsetAsync(deg, 0, (size_t)N_NODES * 4, stream);
    edge_hist<<<E_EDGES / 256, 256, 0, stream>>>(e_dst, deg);
    scan_kernel<<<1, 1024, 0, stream>>>(deg, N_NODES, row_start, cursor);
    edge_scatter<<<E_EDGES / 256, 256, 0, stream>>>(e_src, e_dst, cursor, csr_src);

    unsigned short* y0b = y0h + (size_t)N_NODES * 512;
    unsigned short* y1b = y1h + (size_t)N_NODES * 128;

    // encoder, both passes batched after the two input GEMMs (x, x_shf are
    // separate allocations, so gA runs twice; everything downstream is M=60000)
    gemm_bt<0, 1, 256><<<480, 512, 0, stream>>>(x, 1024, encW0t, N_NODES, 1024, y0h, 512, nullptr, 2);
    gemm_bt<0, 1, 256><<<480, 512, 0, stream>>>(x_shf, 1024, encW0t, N_NODES, 1024, y0b, 512, nullptr, 2);
    csr_agg_ln_h<512, 512, 1><<<15000, 256, 0, stream>>>(y0h, y0b, 60000, row_start, csr_src, encb0, agg0h, 1, 1);
    gemm_bt<1, 1, 128><<<472, 256, 0, stream>>>(agg0h, 512, encW1t, 60000, 512, y1h, 128, nullptr, 1);
    csr_agg_ln_h<128, 128, 1><<<15000, 256, 0, stream>>>(y1h, y1b, 60000, row_start, csr_src, encb1, znh, 1, 1);
    pool_kernel_h<<<15000, 256, 0, stream>>>(znh, subidx, out);

    // batch embedding; decoder agg-1 fuses the concat (reads znh + bembf)
    batch_emb_kernel<<<(N_NODES + 255) / 256, 256, 0, stream>>>(blab, beW0, beb0, beW1, beb1, bembf);
    csr_agg_dec<<<7500, 256, 0, stream>>>(znh, bembf, row_start, csr_src, s1h);

    // decoder
    gemm_bt<1, 1, 256><<<480, 512, 0, stream>>>(s1h, 192, decW0t, N_NODES, 192, y0h, 512, nullptr, 2);
    ln_relu_h512<<<7500, 256, 0, stream>>>(y0h, decb0, y0h);  // in-place
    csr_agg_ln_h<512, 512, 0><<<7500, 256, 0, stream>>>(y0h, y0h, N_NODES, row_start, csr_src, nullptr, agg0h, 1, 0);
    gemm_bt<1, 0, 256><<<960, 512, 0, stream>>>(agg0h, 512, decW1t, N_NODES, 512, out + 7680000, 1024, decb1, 4);

    // heads: bilinear via U = z_sub @ bil_W
    gemm_bt<0, 0, 128><<<240, 256, 0, stream>>>(out, 128, bilWt, N_NODES, 128, Ubil, 128, nullptr, 1);
    bilinear_dot<<<(NPAIR + 3) / 4, 256, 0, stream>>>(Ubil, out + 3840000, posi, negi,
                                                      out + 38400000, out + 38416384);
    bd_kernel<<<7500, 256, 0, stream>>>(out, bdW0, bdb0, bdW1, bdb1, out + 38432768);
}